// Round 12
// baseline (248.978 us; speedup 1.0000x reference)
//
#include <hip/hip_runtime.h>
#include <hip/hip_bf16.h>
#include <hip/hip_fp16.h>

#define GG 8
#define AA 65
#define BB 256

typedef __attribute__((ext_vector_type(8))) short bf16x8;
typedef __attribute__((ext_vector_type(4))) short s16x4;
typedef __attribute__((ext_vector_type(4))) float f32x4;
typedef _Float16 hf2 __attribute__((ext_vector_type(2)));
#define MFMA16(a, b, c) __builtin_amdgcn_mfma_f32_16x16x32_bf16(a, b, c, 0, 0, 0)
#define FDOT2(a, b, c) __builtin_amdgcn_fdot2((a), (b), (c), false)

__device__ __forceinline__ void rz_taps(int o, float scale, int in_size,
                                        int& ia, int& ib, float& f) {
  float pos = (o + 0.5f) * scale - 0.5f;
  float fl = floorf(pos);
  int i0 = (int)fl;
  f = pos - fl;
  ia = i0 < 0 ? 0 : i0;
  int i1 = i0 + 1;
  ib = i1 > (in_size - 1) ? (in_size - 1) : i1;
}

// Compile-time 128->65 tap: pos = (j+0.5)*65/128-0.5 = (130j-63)/256 exactly.
#define JTAP(jc, ja, jb, fj) \
  const int num_ = 130 * (jc) - 63;               \
  const int fl_ = num_ >> 8;                      \
  const int ja = fl_ < 0 ? 0 : fl_;               \
  const int jb = (fl_ + 1 > 64) ? 64 : (fl_ + 1); \
  const float fj = (float)(num_ - (fl_ << 8)) * 0.00390625f;

__device__ __forceinline__ float gelu_exact(float v) {
  return 0.5f * v * (1.0f + erff(v * 0.70710678118654752f));
}

__device__ __forceinline__ short f2b(float f) {
  __hip_bfloat16 h = __float2bfloat16(f);
  return *reinterpret_cast<short*>(&h);
}
__device__ __forceinline__ float b2f(short s) {
  unsigned int u = ((unsigned int)(unsigned short)s) << 16;
  return __uint_as_float(u);
}

#define RSBN 0.99999500003749977f  // 1/sqrt(1+1e-5)

// ---------- PREP: weights->bf16, relA2/relAT2 (fp16 c-pair packed), veA ----------
__global__ void k_prep(const float* __restrict__ base, const float* __restrict__ wq,
                       const float* __restrict__ w1, const float* __restrict__ w2,
                       short* __restrict__ wqb, short* __restrict__ w1b,
                       short* __restrict__ w2b, __half* __restrict__ relA2h,
                       __half* __restrict__ relAT2h, __half* __restrict__ veA) {
  int blk = blockIdx.x;
  int tt = threadIdx.x;
  if (blk < 256) {             // weights
    int i = blk * 256 + tt;
    if (i < 32768) wqb[i] = f2b(wq[i]);
    w1b[i] = f2b(w1[i]);
    w2b[i] = f2b(w2[i]);
    return;
  }
  blk -= 256;
  if (blk < 265) {             // q_emb / k_emb^T, fp16 c-pair dword layout [cp][i][68]
    int idx = blk * 256 + tt;
    if (idx >= 16 * AA * AA) return;
    int j = idx % AA;
    int r = idx / AA;
    int i = r % AA;
    int c = r / AA;
    int ia, ib, ja, jb; float fi, fj;
    rz_taps(i, 255.0f / 65.0f, 255, ia, ib, fi);
    rz_taps(j, 255.0f / 65.0f, 255, ja, jb, fj);
    const float* S = base + (size_t)c * 255 * 255;
    float v = (1.0f - fi) * ((1.0f - fj) * S[ia * 255 + ja] + fj * S[ia * 255 + jb])
            + fi * ((1.0f - fj) * S[ib * 255 + ja] + fj * S[ib * 255 + jb]);
    if (c < 8) {
      relA2h[((((c >> 1) * 4420) + i * 68 + j) << 1) + (c & 1)] = __float2half(v);
    } else {
      int c2 = c - 8;
      relAT2h[((((c2 >> 1) * 4420) + j * 68 + i) << 1) + (c2 & 1)] = __float2half(v);
    }
    return;
  }
  blk -= 265;
  {  // veA[c][ap][128i] half2 (wave-coalesced: i innermost): i-upsampled v_emb
    int idx = blk * 256 + tt;  // 16*66*128 = 135,168
    if (idx >= 16 * 66 * 128) return;
    int i = idx & 127;
    int r = idx >> 7;
    int a = r % 66, c = r / 66;
    float v = 0.f;
    if (a < 65) {
      int ia, ib; float fi;
      rz_taps(i, 65.0f / 128.0f, 65, ia, ib, fi);
      int ja, jb; float fj;
      rz_taps(a, 255.0f / 65.0f, 255, ja, jb, fj);
      int p0a, p0b; float g0;
      rz_taps(ia, 255.0f / 65.0f, 255, p0a, p0b, g0);
      int p1a, p1b; float g1;
      rz_taps(ib, 255.0f / 65.0f, 255, p1a, p1b, g1);
      const float* S = base + (size_t)(16 + c) * 255 * 255;
      float r0 = (1.0f - g0) * ((1.0f - fj) * S[p0a * 255 + ja] + fj * S[p0a * 255 + jb])
               + g0 * ((1.0f - fj) * S[p0b * 255 + ja] + fj * S[p0b * 255 + jb]);
      float r1 = (1.0f - g1) * ((1.0f - fj) * S[p1a * 255 + ja] + fj * S[p1a * 255 + jb])
               + g1 * ((1.0f - fj) * S[p1b * 255 + ja] + fj * S[p1b * 255 + jb]);
      v = (1.0f - fi) * r0 + fi * r1;
    }
    veA[((size_t)(c * 33 + (a >> 1)) * 128 + i) * 2 + (a & 1)] = __float2half(v);
  }
}

// ---------- XA: downsample x along i (128->65) -> xab[n][a][c][w] bf16 ----------
__global__ void k_xa(const float* __restrict__ x, short* __restrict__ xab) {
  int idx = blockIdx.x * 256 + threadIdx.x;  // 2,129,920
  if (idx >= 2 * 65 * 128 * 128) return;
  int w = idx & 127;
  int c = (idx >> 7) & 127;
  int r = idx >> 14;
  int a = r % 65, n = r / 65;
  int ia, ib; float f;
  rz_taps(a, 128.0f / 65.0f, 128, ia, ib, f);
  const float* src = x + ((size_t)(n * 128 + c) * 128) * 128 + w;
  float v = (1.0f - f) * src[(size_t)ia * 128] + f * src[(size_t)ib * 128];
  xab[idx] = f2b(v);
}

// ---------- MFMA GEMM 1: qkva[n][o][a][w] = bf16(BN(Wqkv . xa)) ----------
__global__ __launch_bounds__(256) void k_qkv_mfma(
    const short* __restrict__ xab, const short* __restrict__ wqb,
    const float* __restrict__ bg, const float* __restrict__ bb,
    short* __restrict__ out) {
  const int ob = blockIdx.x * 128;
  const int a = blockIdx.y;
  const int n = blockIdx.z;
  __shared__ short Asm[128 * 40];
  __shared__ short Bsm[128 * 40];
  const int t = threadIdx.x;
  const int lane = t & 63, wv = t >> 6;
  const int wm = wv >> 1, wn = wv & 1;
  const int lr = lane & 15, lk = (lane >> 4) * 8;
  f32x4 acc[4][4];
  #pragma unroll
  for (int i = 0; i < 4; ++i)
    #pragma unroll
    for (int j = 0; j < 4; ++j)
      #pragma unroll
      for (int q = 0; q < 4; ++q) acc[i][j][q] = 0.f;
  const short* X = xab + (size_t)(n * 65 + a) * 128 * 128;
  for (int k0 = 0; k0 < 128; k0 += 32) {
    #pragma unroll
    for (int i2 = 0; i2 < 2; ++i2) {
      int u = t + 256 * i2;
      int row = u >> 2, kq = (u & 3) * 8;
      *(bf16x8*)&Asm[row * 40 + kq] = *(const bf16x8*)&wqb[(ob + row) * 128 + k0 + kq];
    }
    #pragma unroll
    for (int i2 = 0; i2 < 2; ++i2) {
      int u = t + 256 * i2;
      int k = u >> 4, p8 = (u & 15) * 8;
      bf16x8 hv = *(const bf16x8*)&X[(k0 + k) * 128 + p8];
      #pragma unroll
      for (int j = 0; j < 8; ++j) Bsm[(p8 + j) * 40 + k] = hv[j];
    }
    __syncthreads();
    bf16x8 af[4], bfr[4];
    #pragma unroll
    for (int mf = 0; mf < 4; ++mf) af[mf] = *(bf16x8*)&Asm[(wm * 64 + mf * 16 + lr) * 40 + lk];
    #pragma unroll
    for (int nf = 0; nf < 4; ++nf) bfr[nf] = *(bf16x8*)&Bsm[(wn * 64 + nf * 16 + lr) * 40 + lk];
    #pragma unroll
    for (int mf = 0; mf < 4; ++mf)
      #pragma unroll
      for (int nf = 0; nf < 4; ++nf)
        acc[mf][nf] = MFMA16(af[mf], bfr[nf], acc[mf][nf]);
    __syncthreads();
  }
  #pragma unroll
  for (int mf = 0; mf < 4; ++mf) {
    #pragma unroll
    for (int r = 0; r < 4; ++r) {
      int o = ob + wm * 64 + mf * 16 + (lane >> 4) * 4 + r;
      float sc = bg[o] * RSBN, sh = bb[o];
      #pragma unroll
      for (int nf = 0; nf < 4; ++nf) {
        int p = wn * 64 + nf * 16 + lr;
        out[((size_t)(n * 256 + o) * 65 + a) * 128 + p] = f2b(acc[mf][nf][r] * sc + sh);
      }
    }
  }
}

// ---------- F: fused sim(fp16 dot2) + two-pass softmax + streaming sv/sve ----------
__global__ __launch_bounds__(256) void k_attn(
    const short* __restrict__ qkva, const __half* __restrict__ relA2,
    const __half* __restrict__ relAT2, const __half* __restrict__ veA,
    const float* __restrict__ sg, const float* __restrict__ sb,
    const float* __restrict__ og, const float* __restrict__ ob,
    float* __restrict__ yT) {
  int orig = blockIdx.x;
  int bg = ((orig & 7) << 8) + (orig >> 3);  // bijective XCD-chunk swizzle
  int b = bg >> 3, g = bg & 7;
  int n = b >> 7, w = b & 127;
  __shared__ float Ss[65 * 68];          // 17,680 B; reused as PwsH after sync
  __shared__ float u0[536];              // 2,144 B: qs2+ks2; vasH after
  __shared__ float Pinvs[128];           // 512 B -> total 20,336 B => 8 blocks/CU LDS
  __half* PwsH = (__half*)Ss;
  hf2* qs2 = (hf2*)u0;
  hf2* ks2v = (hf2*)(u0 + 260);
  float* ks2f = u0 + 260;
  __half* vasH = (__half*)u0;
  int t = threadIdx.x;
  const short* Qbase = qkva + ((size_t)(n * 256 + g * 32) * 65) * 128 + w;

  // phase 1: stage q,k as fp16 c-pairs
  for (int l = t; l < 520; l += 256) {
    int isQ = (l < 260);
    int u2 = isQ ? l : l - 260;
    int cp = u2 / 65, a = u2 - cp * 65;
    int cbase = (cp << 1) + (isQ ? 0 : 8);
    float v0 = b2f(Qbase[(size_t)(cbase * 65 + a) * 128]);
    float v1 = b2f(Qbase[(size_t)((cbase + 1) * 65 + a) * 128]);
    hf2 h;
    h[0] = (_Float16)v0;
    h[1] = (_Float16)v1;
    if (isQ) qs2[cp * 65 + a] = h;
    else ks2v[cp * 68 + a] = h;
  }
  __syncthreads();

  // phase 2: sim 65x65 via packed fdot2 (qk+qr+kr, BN-combined)
  {
    float sqk = sg[g] * RSBN, sqr = sg[8 + g] * RSBN, skr = sg[16 + g] * RSBN;
    float badd = sb[g] + sb[8 + g] + sb[16 + g];
    const float* rAf = (const float*)relA2;
    const float* rTf = (const float*)relAT2;
    const hf2* rAv = (const hf2*)relA2;
    const hf2* rTv = (const hf2*)relAT2;
    for (int u = t; u < 65 * 17; u += 256) {
      int i = u / 17, jq = u - i * 17;
      hf2 q2[4];
      #pragma unroll
      for (int cp = 0; cp < 4; ++cp) q2[cp] = qs2[cp * 65 + i];
      if (jq < 16) {
        int j0 = jq * 4;
        int lofs = i * 68 + j0;
        float qk0 = 0, qk1 = 0, qk2 = 0, qk3 = 0;
        float qr0 = 0, qr1 = 0, qr2 = 0, qr3 = 0;
        float kr0 = 0, kr1 = 0, kr2 = 0, kr3 = 0;
        #pragma unroll
        for (int cp = 0; cp < 4; ++cp) {
          float4 kq = *(const float4*)&ks2f[cp * 68 + j0];
          float4 ra = *(const float4*)&rAf[cp * 4420 + lofs];
          float4 rt = *(const float4*)&rTf[cp * 4420 + lofs];
          hf2 k0 = __builtin_bit_cast(hf2, kq.x);
          hf2 k1 = __builtin_bit_cast(hf2, kq.y);
          hf2 k2h = __builtin_bit_cast(hf2, kq.z);
          hf2 k3 = __builtin_bit_cast(hf2, kq.w);
          qk0 = FDOT2(k0, q2[cp], qk0);
          qk1 = FDOT2(k1, q2[cp], qk1);
          qk2 = FDOT2(k2h, q2[cp], qk2);
          qk3 = FDOT2(k3, q2[cp], qk3);
          qr0 = FDOT2(__builtin_bit_cast(hf2, ra.x), q2[cp], qr0);
          qr1 = FDOT2(__builtin_bit_cast(hf2, ra.y), q2[cp], qr1);
          qr2 = FDOT2(__builtin_bit_cast(hf2, ra.z), q2[cp], qr2);
          qr3 = FDOT2(__builtin_bit_cast(hf2, ra.w), q2[cp], qr3);
          kr0 = FDOT2(__builtin_bit_cast(hf2, rt.x), k0, kr0);
          kr1 = FDOT2(__builtin_bit_cast(hf2, rt.y), k1, kr1);
          kr2 = FDOT2(__builtin_bit_cast(hf2, rt.z), k2h, kr2);
          kr3 = FDOT2(__builtin_bit_cast(hf2, rt.w), k3, kr3);
        }
        float4 res;
        res.x = sqk * qk0 + sqr * qr0 + skr * kr0 + badd;
        res.y = sqk * qk1 + sqr * qr1 + skr * kr1 + badd;
        res.z = sqk * qk2 + sqr * qr2 + skr * kr2 + badd;
        res.w = sqk * qk3 + sqr * qr3 + skr * kr3 + badd;
        *(float4*)&Ss[lofs] = res;
      } else {
        int lofs = i * 68 + 64;
        float qk = 0, qr = 0, kr = 0;
        #pragma unroll
        for (int cp = 0; cp < 4; ++cp) {
          hf2 kv = ks2v[cp * 68 + 64];
          qk = FDOT2(kv, q2[cp], qk);
          qr = FDOT2(rAv[cp * 4420 + lofs], q2[cp], qr);
          kr = FDOT2(rTv[cp * 4420 + lofs], kv, kr);
        }
        Ss[lofs] = sqk * qk + sqr * qr + skr * kr + badd;
      }
    }
  }
  __syncthreads();

  // phase 3: v stage (overlays u0) + TWO-PASS register-T softmax fold
  for (int l = t; l < 16 * 66; l += 256) {
    int c = l / 66, a = l - c * 66;
    float v = (a < 65) ? b2f(Qbase[(size_t)((16 + c) * 65 + a) * 128]) : 0.f;
    vasH[l] = __float2half(v);
  }
  {
    const int i = t >> 1, h = t & 1;
    int ia, ib; float fi;
    rz_taps(i, 65.0f / 128.0f, 65, ia, ib, fi);
    const float* r0 = Ss + ia * 68 + h * 32;
    const float* r1 = Ss + ib * 68 + h * 32;
    const float wi0 = 1.0f - fi;
    // stabilizer: max over both source rows >= max over any lerped value (valid bound)
    float mx = -1e30f;
    #pragma unroll
    for (int k = 0; k < 33; ++k) mx = fmaxf(mx, fmaxf(r0[k], r1[k]));
    mx = fmaxf(mx, __shfl_xor(mx, 1));
    float sum = 0.f;
    float pA[17];
    // ---- pass A: first 32 j of this half -> a-window [0,16] (rel. h*32) ----
    {
      float T[17];
      #pragma unroll
      for (int k = 0; k < 17; ++k) { T[k] = wi0 * r0[k] + fi * r1[k]; pA[k] = 0.f; }
      if (h == 0) {
        #pragma unroll
        for (int j = 0; j < 32; ++j) {
          JTAP(j, ja, jb, fj);
          float e = __expf((1.0f - fj) * T[ja] + fj * T[jb] - mx);
          sum += e; pA[ja] += e * (1.0f - fj); pA[jb] += e * fj;
        }
      } else {
        #pragma unroll
        for (int j = 64; j < 96; ++j) {
          JTAP(j, ja, jb, fj);
          float e = __expf((1.0f - fj) * T[ja - 32] + fj * T[jb - 32] - mx);
          sum += e; pA[ja - 32] += e * (1.0f - fj); pA[jb - 32] += e * fj;
        }
      }
    }
    // ---- pass B: second 32 j -> a-window [16,32] (rel.) ----
    float pB[17];
    {
      float T[17];
      #pragma unroll
      for (int k = 0; k < 17; ++k) { T[k] = wi0 * r0[16 + k] + fi * r1[16 + k]; pB[k] = 0.f; }
      if (h == 0) {
        #pragma unroll
        for (int j = 32; j < 64; ++j) {
          JTAP(j, ja, jb, fj);
          float e = __expf((1.0f - fj) * T[ja - 16] + fj * T[jb - 16] - mx);
          sum += e; pB[ja - 16] += e * (1.0f - fj); pB[jb - 16] += e * fj;
        }
      } else {
        #pragma unroll
        for (int j = 96; j < 128; ++j) {
          JTAP(j, ja, jb, fj);
          float e = __expf((1.0f - fj) * T[ja - 48] + fj * T[jb - 48] - mx);
          sum += e; pB[ja - 48] += e * (1.0f - fj); pB[jb - 48] += e * fj;
        }
      }
    }
    sum += __shfl_xor(sum, 1);
    float other = __shfl_xor(h ? pA[0] : pB[16], 1);
    __syncthreads();   // all Ss reads complete before PwsH overwrites the same LDS
    __half* prow = &PwsH[i * 66];
    if (h == 0) {
      #pragma unroll
      for (int k = 0; k < 16; ++k) prow[k] = __float2half(pA[k]);
      prow[16] = __float2half(pA[16] + pB[0]);
      #pragma unroll
      for (int k = 1; k < 16; ++k) prow[16 + k] = __float2half(pB[k]);
      prow[32] = __float2half(pB[16] + other);
      Pinvs[i] = 1.0f / sum;
    } else {
      prow[32] = __float2half(pA[0] + other);
      #pragma unroll
      for (int k = 1; k < 16; ++k) prow[32 + k] = __float2half(pA[k]);
      prow[48] = __float2half(pA[16] + pB[0]);
      #pragma unroll
      for (int k = 1; k < 17; ++k) prow[48 + k] = __float2half(pB[k]);
      prow[65] = __float2half(0.f);
    }
  }
  __syncthreads();

  // phase 4: streaming dot2 contraction (pw read per-ap, 16 accumulators)
  {
    const int i = t & 127;
    const int cg = t >> 7;
    const float inv = Pinvs[i];
    const hf2* prow2 = (const hf2*)&PwsH[i * 66];
    const hf2* vas2 = (const hf2*)vasH;
    const hf2* vpb = (const hf2*)veA + i;
    float sv[8], se[8];
    #pragma unroll
    for (int l = 0; l < 8; ++l) { sv[l] = 0.f; se[l] = 0.f; }
    #pragma unroll
    for (int ap = 0; ap < 33; ++ap) {
      hf2 pw = prow2[ap];
      #pragma unroll
      for (int l = 0; l < 8; ++l) {
        const int c = cg * 8 + l;
        sv[l] = FDOT2(vas2[c * 33 + ap], pw, sv[l]);
        se[l] = FDOT2(vpb[(size_t)(c * 33 + ap) * 128], pw, se[l]);
      }
    }
    #pragma unroll
    for (int l = 0; l < 8; ++l) {
      int c2 = g * 16 + cg * 8 + l;
      int o0 = 2 * c2;
      float val = og[o0] * RSBN * (sv[l] * inv) + ob[o0]
                + og[o0 + 1] * RSBN * (se[l] * inv) + ob[o0 + 1];
      yT[((size_t)(n * 128 + c2)) * 16384 + w * 128 + i] = val;
    }
  }
}

// ---------- XS: stage yT plane (fp32 LDS), emit xnb (shift+IN, bf16) + yStd (fp32) ----------
__global__ __launch_bounds__(256) void k_xs(const float* __restrict__ yT,
                                            const float* __restrict__ inw,
                                            const float* __restrict__ inb,
                                            short* __restrict__ xnb,
                                            float* __restrict__ yStd) {
  int gid = blockIdx.x;
  int n, cs, cx = -1;
  bool wStd;
  if (gid < 256) {
    n = gid >> 7; cx = gid & 127;
    cs = (cx < 40) ? (cx % 10) : cx;
    wStd = (cx < 10) || (cx >= 40);
  } else {
    int u = gid - 256;
    n = u / 30; cs = 10 + (u % 30);
    wStd = true;
  }
  int dh = 0, dw = 0;
  if (cx >= 0) {
    if (cx < 10)       dw = -2;
    else if (cx < 20)  dw = 2;
    else if (cx < 30)  dh = -2;
    else if (cx < 40)  dh = 2;
  }
  __shared__ float Sb[128 * 130];
  __shared__ float sm[8];
  const float* src = yT + ((size_t)(n * 128 + cs)) * 16384;
  int t = threadIdx.x;
  #pragma unroll
  for (int l = 0; l < 16; ++l) {
    int q = t + l * 256;
    float4 v = *(const float4*)&src[q * 4];
    int w = q >> 5, i0 = (q * 4) & 127;
    float* d = &Sb[w * 130 + i0];
    *(float2*)d = make_float2(v.x, v.y);
    *(float2*)(d + 2) = make_float2(v.z, v.w);
  }
  __syncthreads();
  if (wStd) {
    float* dst = yStd + ((size_t)(n * 128 + cs)) * 16384;
    for (int l = 0; l < 64; ++l) {
      int idx = t + l * 256;
      int h = idx >> 7, w = idx & 127;
      dst[idx] = Sb[w * 130 + h];
    }
  }
  if (cx >= 0) {
    float s = 0.f, q2 = 0.f;
    for (int l = 0; l < 64; ++l) {
      int idx = t + l * 256;
      int h = idx >> 7, w = idx & 127;
      int hs = h + dh, ws = w + dw;
      float v = (hs >= 0 && hs < 128 && ws >= 0 && ws < 128) ? Sb[ws * 130 + hs] : 0.f;
      s += v; q2 += v * v;
    }
    #pragma unroll
    for (int o = 32; o; o >>= 1) { s += __shfl_down(s, o); q2 += __shfl_down(q2, o); }
    if ((t & 63) == 0) { sm[(t >> 6) * 2] = s; sm[(t >> 6) * 2 + 1] = q2; }
    __syncthreads();
    float S_ = sm[0] + sm[2] + sm[4] + sm[6];
    float Q_ = sm[1] + sm[3] + sm[5] + sm[7];
    float mean = S_ * (1.0f / 16384.0f);
    float var = Q_ * (1.0f / 16384.0f) - mean * mean;
    float scale = inw[cx] * rsqrtf(var + 1e-5f);
    float shift = inb[cx] - mean * scale;
    short* dst = xnb + ((size_t)(n * 128 + cx)) * 16384;
    for (int l = 0; l < 64; ++l) {
      int idx = t + l * 256;
      int h = idx >> 7, w = idx & 127;
      int hs = h + dh, ws = w + dw;
      float v = (hs >= 0 && hs < 128 && ws >= 0 && ws < 128) ? Sb[ws * 130 + hs] : 0.f;
      dst[idx] = f2b(v * scale + shift);
    }
  }
}

// ---------- MFMA GEMM 2: h1 = gelu(W1 . xn) ----------
__global__ __launch_bounds__(256) void k_mlp1_mfma(
    const short* __restrict__ xnb, const short* __restrict__ w1b,
    short* __restrict__ h1) {
  const int ob = blockIdx.x * 128;
  const int pb = blockIdx.y * 128;
  const int n = blockIdx.z;
  __shared__ short Asm[128 * 40];
  __shared__ short Bsm[128 * 40];
  const int t = threadIdx.x;
  const int lane = t & 63, wv = t >> 6;
  const int wm = wv >> 1, wn = wv & 1;
  const int lr = lane & 15, lk = (lane >> 4) * 8;
  f32x4 acc[4][4];
  #pragma unroll
  for (int i = 0; i < 4; ++i)
    #pragma unroll
    for (int j = 0; j < 4; ++j)
      #pragma unroll
      for (int q = 0; q < 4; ++q) acc[i][j][q] = 0.f;
  const short* X = xnb + (size_t)n * 128 * 16384;
  for (int k0 = 0; k0 < 128; k0 += 32) {
    #pragma unroll
    for (int i2 = 0; i2 < 2; ++i2) {
      int u = t + 256 * i2;
      int row = u >> 2, kq = (u & 3) * 8;
      *(bf16x8*)&Asm[row * 40 + kq] = *(const bf16x8*)&w1b[(ob + row) * 128 + k0 + kq];
    }
    #pragma unroll
    for (int i2 = 0; i2 < 2; ++i2) {
      int u = t + 256 * i2;
      int k = u >> 4, p8 = (u & 15) * 8;
      bf16x8 hv = *(const bf16x8*)&X[(size_t)(k0 + k) * 16384 + pb + p8];
      #pragma unroll
      for (int j = 0; j < 8; ++j) Bsm[(p8 + j) * 40 + k] = hv[j];
    }
    __syncthreads();
    bf16x8 af[4], bfr[4];
    #pragma unroll
    for (int mf = 0; mf < 4; ++mf) af[mf] = *(bf16x8*)&Asm[(wm * 64 + mf * 16 + lr) * 40 + lk];
    #pragma unroll
    for (int nf = 0; nf < 4; ++nf) bfr[nf] = *(bf16x8*)&Bsm[(wn * 64 + nf * 16 + lr) * 40 + lk];
    #pragma unroll
    for (int mf = 0; mf < 4; ++mf)
      #pragma unroll
      for (int nf = 0; nf < 4; ++nf)
        acc[mf][nf] = MFMA16(af[mf], bfr[nf], acc[mf][nf]);
    __syncthreads();
  }
  #pragma unroll
  for (int mf = 0; mf < 4; ++mf)
    #pragma unroll
    for (int r = 0; r < 4; ++r) {
      int o = ob + wm * 64 + mf * 16 + (lane >> 4) * 4 + r;
      #pragma unroll
      for (int nf = 0; nf < 4; ++nf) {
        int p = pb + wn * 64 + nf * 16 + lr;
        h1[((size_t)(n * 512 + o)) * 16384 + p] = f2b(gelu_exact(acc[mf][nf][r]));
      }
    }
}

// ---------- MFMA GEMM 3: out = W2 . h1 + identity(yStd) ----------
__global__ __launch_bounds__(256) void k_mlp2_mfma(
    const short* __restrict__ h1, const short* __restrict__ w2b,
    const float* __restrict__ y, float* __restrict__ out) {
  const int pb = blockIdx.x * 128;
  const int ob = blockIdx.y * 128;
  const int n = blockIdx.z;
  __shared__ short Asm[128 * 40];
  __shared__ short Bsm[128 * 40];
  const int t = threadIdx.x;
  const int lane = t & 63, wv = t >> 6;
  const int wm = wv >> 1, wn = wv & 1;
  const int lr = lane & 15, lk = (lane >> 4) * 8;
  f32x4 acc[4][4];
  #pragma unroll
  for (int i = 0; i < 4; ++i)
    #pragma unroll
    for (int j = 0; j < 4; ++j)
      #pragma unroll
      for (int q = 0; q < 4; ++q) acc[i][j][q] = 0.f;
  const short* H = h1 + (size_t)n * 512 * 16384;
  for (int k0 = 0; k0 < 512; k0 += 32) {
    #pragma unroll
    for (int i2 = 0; i2 < 2; ++i2) {
      int u = t + 256 * i2;
      int row = u >> 2, kq = (u & 3) * 8;
      *(bf16x8*)&Asm[row * 40 + kq] = *(const bf16x8*)&w2b[(ob + row) * 512 + k0 + kq];
    }
    #pragma unroll
    for (int i2 = 0; i2 < 2; ++i2) {
      int u = t + 256 * i2;
      int k = u >> 4, p8 = (u & 15) * 8;
      bf16x8 hv = *(const bf16x8*)&H[(size_t)(k0 + k) * 16384 + pb + p8];
      #pragma unroll
      for (int j = 0; j < 8; ++j) Bsm[(p8 + j) * 40 + k] = hv[j];
    }
    __syncthreads();
    bf16x8 af[4], bfr[4];
    #pragma unroll
    for (int mf = 0; mf < 4; ++mf) af[mf] = *(bf16x8*)&Asm[(wm * 64 + mf * 16 + lr) * 40 + lk];
    #pragma unroll
    for (int nf = 0; nf < 4; ++nf) bfr[nf] = *(bf16x8*)&Bsm[(wn * 64 + nf * 16 + lr) * 40 + lk];
    #pragma unroll
    for (int mf = 0; mf < 4; ++mf)
      #pragma unroll
      for (int nf = 0; nf < 4; ++nf)
        acc[mf][nf] = MFMA16(af[mf], bfr[nf], acc[mf][nf]);
    __syncthreads();
  }
  #pragma unroll
  for (int mf = 0; mf < 4; ++mf)
    #pragma unroll
    for (int r = 0; r < 4; ++r) {
      int o = ob + wm * 64 + mf * 16 + (lane >> 4) * 4 + r;
      #pragma unroll
      for (int nf = 0; nf < 4; ++nf) {
        int p = pb + wn * 64 + nf * 16 + lr;
        size_t base = ((size_t)(n * 128 + o)) * 16384 + p;
        out[base] = acc[mf][nf][r] + y[base];
      }
    }
}

extern "C" void kernel_launch(void* const* d_in, const int* in_sizes, int n_in,
                              void* d_out, int out_size, void* d_ws, size_t ws_size,
                              hipStream_t stream) {
  const float* x        = (const float*)d_in[0];
  const float* w_qkv    = (const float*)d_in[1];
  const float* bn_qkv_g = (const float*)d_in[2];
  const float* bn_qkv_b = (const float*)d_in[3];
  const float* bn_sim_g = (const float*)d_in[4];
  const float* bn_sim_b = (const float*)d_in[5];
  const float* bn_out_g = (const float*)d_in[6];
  const float* bn_out_b = (const float*)d_in[7];
  const float* in_w     = (const float*)d_in[8];
  const float* in_b     = (const float*)d_in[9];
  const float* mlp_w1   = (const float*)d_in[10];
  const float* mlp_w2   = (const float*)d_in[11];
  const float* base_rel = (const float*)d_in[12];
  float* Wp = (float*)d_ws;

  __half* relA2  = (__half*)(Wp + 0);        // 17,680 f
  __half* relAT2 = (__half*)(Wp + 17680);    // 17,680 f
  __half* veA    = (__half*)(Wp + 35360);    // 67,584 f
  float* yT      = Wp + 102944;              // 4,194,304
  float* yStd    = Wp + 4297248;             // 4,194,304
  short* wqb     = (short*)(Wp + 8491552);   // 32,768 shorts
  short* w1b     = (short*)(Wp + 8507936);   // 65,536 shorts
  short* w2b     = (short*)(Wp + 8540704);   // 65,536 shorts
  short* xnb     = (short*)(Wp + 8573472);   // 4,194,304 shorts
  short* xab     = (short*)(Wp + 10670624);  // 2,129,920 shorts (dead after qkv)
  short* qkva    = (short*)(Wp + 11735584);  // 4,259,840 shorts (dead after attn)
  short* h1b     = (short*)(Wp + 10670624);  // 16,777,216 shorts (overlays xab+qkva)
  // peak: 19,059,232 floats = 76.2 MB

  k_prep<<<dim3(1049), dim3(256), 0, stream>>>(base_rel, w_qkv, mlp_w1, mlp_w2,
                                               wqb, w1b, w2b, relA2, relAT2, veA);
  k_xa<<<dim3(8320), dim3(256), 0, stream>>>(x, xab);
  k_qkv_mfma<<<dim3(2, 65, 2), dim3(256), 0, stream>>>(xab, wqb, bn_qkv_g, bn_qkv_b, qkva);
  k_attn<<<dim3(2048), dim3(256), 0, stream>>>(qkva, relA2, relAT2, veA,
                                               bn_sim_g, bn_sim_b, bn_out_g, bn_out_b, yT);
  k_xs<<<dim3(316), dim3(256), 0, stream>>>(yT, in_w, in_b, xnb, yStd);
  k_mlp1_mfma<<<dim3(4, 128, 2), dim3(256), 0, stream>>>(xnb, w1b, h1b);
  k_mlp2_mfma<<<dim3(128, 1, 2), dim3(256), 0, stream>>>(h1b, w2b, yStd, (float*)d_out);
}

// Round 13
// 180.104 us; speedup vs baseline: 1.3824x; 1.3824x over previous
//
#include <hip/hip_runtime.h>
#include <hip/hip_bf16.h>
#include <hip/hip_fp16.h>

#define GG 8
#define AA 65
#define BB 256

typedef __attribute__((ext_vector_type(8))) short bf16x8;
typedef __attribute__((ext_vector_type(4))) short s16x4;
typedef __attribute__((ext_vector_type(4))) float f32x4;
typedef _Float16 hf2 __attribute__((ext_vector_type(2)));
#define MFMA16(a, b, c) __builtin_amdgcn_mfma_f32_16x16x32_bf16(a, b, c, 0, 0, 0)
#define FDOT2(a, b, c) __builtin_amdgcn_fdot2((a), (b), (c), false)

__device__ __forceinline__ void rz_taps(int o, float scale, int in_size,
                                        int& ia, int& ib, float& f) {
  float pos = (o + 0.5f) * scale - 0.5f;
  float fl = floorf(pos);
  int i0 = (int)fl;
  f = pos - fl;
  ia = i0 < 0 ? 0 : i0;
  int i1 = i0 + 1;
  ib = i1 > (in_size - 1) ? (in_size - 1) : i1;
}

// Compile-time 128->65 tap: pos = (j+0.5)*65/128-0.5 = (130j-63)/256 exactly.
#define JTAP(jc, ja, jb, fj) \
  const int num_ = 130 * (jc) - 63;               \
  const int fl_ = num_ >> 8;                      \
  const int ja = fl_ < 0 ? 0 : fl_;               \
  const int jb = (fl_ + 1 > 64) ? 64 : (fl_ + 1); \
  const float fj = (float)(num_ - (fl_ << 8)) * 0.00390625f;

__device__ __forceinline__ float gelu_exact(float v) {
  return 0.5f * v * (1.0f + erff(v * 0.70710678118654752f));
}

__device__ __forceinline__ short f2b(float f) {
  __hip_bfloat16 h = __float2bfloat16(f);
  return *reinterpret_cast<short*>(&h);
}
__device__ __forceinline__ float b2f(short s) {
  unsigned int u = ((unsigned int)(unsigned short)s) << 16;
  return __uint_as_float(u);
}

#define RSBN 0.99999500003749977f  // 1/sqrt(1+1e-5)

// ---------- PREP: weights->bf16, relAp/relATp (fp32 padded), veA (wave-coalesced) ----------
__global__ void k_prep(const float* __restrict__ base, const float* __restrict__ wq,
                       const float* __restrict__ w1, const float* __restrict__ w2,
                       short* __restrict__ wqb, short* __restrict__ w1b,
                       short* __restrict__ w2b, float* __restrict__ relAp,
                       float* __restrict__ relATp, __half* __restrict__ veA) {
  int blk = blockIdx.x;
  int tt = threadIdx.x;
  if (blk < 256) {             // weights
    int i = blk * 256 + tt;
    if (i < 32768) wqb[i] = f2b(wq[i]);
    w1b[i] = f2b(w1[i]);
    w2b[i] = f2b(w2[i]);
    return;
  }
  blk -= 256;
  if (blk < 265) {             // q_emb padded + k_emb transposed padded (65x65)
    int idx = blk * 256 + tt;
    if (idx >= 16 * AA * AA) return;
    int j = idx % AA;
    int r = idx / AA;
    int i = r % AA;
    int c = r / AA;
    int ia, ib, ja, jb; float fi, fj;
    rz_taps(i, 255.0f / 65.0f, 255, ia, ib, fi);
    rz_taps(j, 255.0f / 65.0f, 255, ja, jb, fj);
    const float* S = base + (size_t)c * 255 * 255;
    float v = (1.0f - fi) * ((1.0f - fj) * S[ia * 255 + ja] + fj * S[ia * 255 + jb])
            + fi * ((1.0f - fj) * S[ib * 255 + ja] + fj * S[ib * 255 + jb]);
    if (c < 8) relAp[c * 4420 + i * 68 + j] = v;
    else relATp[(c - 8) * 4420 + j * 68 + i] = v;
    return;
  }
  blk -= 265;
  {  // veA[c][ap][128i] half2 (wave-coalesced: i innermost): i-upsampled v_emb
    int idx = blk * 256 + tt;  // 16*66*128 = 135,168
    if (idx >= 16 * 66 * 128) return;
    int i = idx & 127;
    int r = idx >> 7;
    int a = r % 66, c = r / 66;
    float v = 0.f;
    if (a < 65) {
      int ia, ib; float fi;
      rz_taps(i, 65.0f / 128.0f, 65, ia, ib, fi);
      int ja, jb; float fj;
      rz_taps(a, 255.0f / 65.0f, 255, ja, jb, fj);
      int p0a, p0b; float g0;
      rz_taps(ia, 255.0f / 65.0f, 255, p0a, p0b, g0);
      int p1a, p1b; float g1;
      rz_taps(ib, 255.0f / 65.0f, 255, p1a, p1b, g1);
      const float* S = base + (size_t)(16 + c) * 255 * 255;
      float r0 = (1.0f - g0) * ((1.0f - fj) * S[p0a * 255 + ja] + fj * S[p0a * 255 + jb])
               + g0 * ((1.0f - fj) * S[p0b * 255 + ja] + fj * S[p0b * 255 + jb]);
      float r1 = (1.0f - g1) * ((1.0f - fj) * S[p1a * 255 + ja] + fj * S[p1a * 255 + jb])
               + g1 * ((1.0f - fj) * S[p1b * 255 + ja] + fj * S[p1b * 255 + jb]);
      v = (1.0f - fi) * r0 + fi * r1;
    }
    veA[((size_t)(c * 33 + (a >> 1)) * 128 + i) * 2 + (a & 1)] = __float2half(v);
  }
}

// ---------- XA: downsample x along i (128->65) -> xab[n][a][c][w] bf16 ----------
__global__ void k_xa(const float* __restrict__ x, short* __restrict__ xab) {
  int idx = blockIdx.x * 256 + threadIdx.x;  // 2,129,920
  if (idx >= 2 * 65 * 128 * 128) return;
  int w = idx & 127;
  int c = (idx >> 7) & 127;
  int r = idx >> 14;
  int a = r % 65, n = r / 65;
  int ia, ib; float f;
  rz_taps(a, 128.0f / 65.0f, 128, ia, ib, f);
  const float* src = x + ((size_t)(n * 128 + c) * 128) * 128 + w;
  float v = (1.0f - f) * src[(size_t)ia * 128] + f * src[(size_t)ib * 128];
  xab[idx] = f2b(v);
}

// ---------- MFMA GEMM 1: qkva[n][o][a][w] = bf16(BN(Wqkv . xa)) ----------
__global__ __launch_bounds__(256) void k_qkv_mfma(
    const short* __restrict__ xab, const short* __restrict__ wqb,
    const float* __restrict__ bg, const float* __restrict__ bb,
    short* __restrict__ out) {
  const int ob = blockIdx.x * 128;
  const int a = blockIdx.y;
  const int n = blockIdx.z;
  __shared__ short Asm[128 * 40];
  __shared__ short Bsm[128 * 40];
  const int t = threadIdx.x;
  const int lane = t & 63, wv = t >> 6;
  const int wm = wv >> 1, wn = wv & 1;
  const int lr = lane & 15, lk = (lane >> 4) * 8;
  f32x4 acc[4][4];
  #pragma unroll
  for (int i = 0; i < 4; ++i)
    #pragma unroll
    for (int j = 0; j < 4; ++j)
      #pragma unroll
      for (int q = 0; q < 4; ++q) acc[i][j][q] = 0.f;
  const short* X = xab + (size_t)(n * 65 + a) * 128 * 128;
  for (int k0 = 0; k0 < 128; k0 += 32) {
    #pragma unroll
    for (int i2 = 0; i2 < 2; ++i2) {
      int u = t + 256 * i2;
      int row = u >> 2, kq = (u & 3) * 8;
      *(bf16x8*)&Asm[row * 40 + kq] = *(const bf16x8*)&wqb[(ob + row) * 128 + k0 + kq];
    }
    #pragma unroll
    for (int i2 = 0; i2 < 2; ++i2) {
      int u = t + 256 * i2;
      int k = u >> 4, p8 = (u & 15) * 8;
      bf16x8 hv = *(const bf16x8*)&X[(k0 + k) * 128 + p8];
      #pragma unroll
      for (int j = 0; j < 8; ++j) Bsm[(p8 + j) * 40 + k] = hv[j];
    }
    __syncthreads();
    bf16x8 af[4], bfr[4];
    #pragma unroll
    for (int mf = 0; mf < 4; ++mf) af[mf] = *(bf16x8*)&Asm[(wm * 64 + mf * 16 + lr) * 40 + lk];
    #pragma unroll
    for (int nf = 0; nf < 4; ++nf) bfr[nf] = *(bf16x8*)&Bsm[(wn * 64 + nf * 16 + lr) * 40 + lk];
    #pragma unroll
    for (int mf = 0; mf < 4; ++mf)
      #pragma unroll
      for (int nf = 0; nf < 4; ++nf)
        acc[mf][nf] = MFMA16(af[mf], bfr[nf], acc[mf][nf]);
    __syncthreads();
  }
  #pragma unroll
  for (int mf = 0; mf < 4; ++mf) {
    #pragma unroll
    for (int r = 0; r < 4; ++r) {
      int o = ob + wm * 64 + mf * 16 + (lane >> 4) * 4 + r;
      float sc = bg[o] * RSBN, sh = bb[o];
      #pragma unroll
      for (int nf = 0; nf < 4; ++nf) {
        int p = wn * 64 + nf * 16 + lr;
        out[((size_t)(n * 256 + o) * 65 + a) * 128 + p] = f2b(acc[mf][nf][r] * sc + sh);
      }
    }
  }
}

// ---------- F: fused sim + softmax + dot2 sv/sve + bn_out (Ss/Pw LDS union) ----------
__global__ void k_attn(const short* __restrict__ qkva, const float* __restrict__ relAp,
                       const float* __restrict__ relATp, const __half* __restrict__ veA,
                       const float* __restrict__ sg, const float* __restrict__ sb,
                       const float* __restrict__ og, const float* __restrict__ ob,
                       float* __restrict__ yT) {
  int orig = blockIdx.x;
  int bg = ((orig & 7) << 8) + (orig >> 3);  // bijective XCD-chunk swizzle
  int b = bg >> 3, g = bg & 7;
  int n = b >> 7, w = b & 127;
  __shared__ float Ss[65 * 68];          // 17,680 B; reused as PwsH after sync
  __shared__ float u0[1088];             // qs(520)|ksp(544); vasH (16*66 halves) after
  __shared__ float Pinvs[128];
  __half* PwsH = (__half*)Ss;
  float* qs = u0;
  float* ksp = u0 + 520;
  __half* vasH = (__half*)u0;
  int t = threadIdx.x;
  const short* Qbase = qkva + ((size_t)(n * 256 + g * 32) * 65) * 128 + w;

  // phase 1: stage q (ch 0..7) and k (ch 8..15) from qkva
  for (int l = t; l < 1040; l += 256) {
    int cc = l / 65, a = l - cc * 65;
    float v = b2f(Qbase[(size_t)l * 128]);
    if (cc < 8) qs[cc * 65 + a] = v;
    else ksp[(cc - 8) * 68 + a] = v;
  }
  __syncthreads();

  // phase 2: sim 65x65 (BN-combined qk+qr+kr), j-quad vectorized
  {
    float sqk = sg[g] * RSBN, sqr = sg[8 + g] * RSBN, skr = sg[16 + g] * RSBN;
    float badd = sb[g] + sb[8 + g] + sb[16 + g];
    for (int u = t; u < 65 * 17; u += 256) {
      int i = u / 17, jq = u - i * 17;
      float qv[8];
      #pragma unroll
      for (int c = 0; c < 8; ++c) qv[c] = qs[c * 65 + i];
      if (jq < 16) {
        int j0 = jq * 4;
        int lofs = i * 68 + j0;
        float qk0 = 0, qk1 = 0, qk2 = 0, qk3 = 0;
        float qr0 = 0, qr1 = 0, qr2 = 0, qr3 = 0;
        float kr0 = 0, kr1 = 0, kr2 = 0, kr3 = 0;
        #pragma unroll
        for (int c = 0; c < 8; ++c) {
          float4 kv = *(const float4*)&ksp[c * 68 + j0];
          float4 ra = *(const float4*)&relAp[c * 4420 + lofs];
          float4 rt = *(const float4*)&relATp[c * 4420 + lofs];
          float q = qv[c];
          qk0 += q * kv.x; qk1 += q * kv.y; qk2 += q * kv.z; qk3 += q * kv.w;
          qr0 += q * ra.x; qr1 += q * ra.y; qr2 += q * ra.z; qr3 += q * ra.w;
          kr0 += kv.x * rt.x; kr1 += kv.y * rt.y; kr2 += kv.z * rt.z; kr3 += kv.w * rt.w;
        }
        float4 res;
        res.x = sqk * qk0 + sqr * qr0 + skr * kr0 + badd;
        res.y = sqk * qk1 + sqr * qr1 + skr * kr1 + badd;
        res.z = sqk * qk2 + sqr * qr2 + skr * kr2 + badd;
        res.w = sqk * qk3 + sqr * qr3 + skr * kr3 + badd;
        *(float4*)&Ss[lofs] = res;
      } else {
        float qk = 0, qr = 0, kr = 0;
        int lofs = i * 68 + 64;
        #pragma unroll
        for (int c = 0; c < 8; ++c) {
          float kv = ksp[c * 68 + 64];
          qk += qv[c] * kv;
          qr += qv[c] * relAp[c * 4420 + lofs];
          kr += kv * relATp[c * 4420 + lofs];
        }
        Ss[lofs] = sqk * qk + sqr * qr + skr * kr + badd;
      }
    }
  }
  __syncthreads();

  // phase 3: v stage (overlays u0) + register-T softmax fold (Pw overwrites Ss after sync)
  for (int l = t; l < 16 * 66; l += 256) {
    int c = l / 66, a = l - c * 66;
    float v = (a < 65) ? b2f(Qbase[(size_t)((16 + c) * 65 + a) * 128]) : 0.f;
    vasH[l] = __float2half(v);
  }
  {
    const int i = t >> 1, h = t & 1;
    int ia, ib; float fi;
    rz_taps(i, 65.0f / 128.0f, 65, ia, ib, fi);
    const float* r0 = Ss + ia * 68 + h * 32;
    const float* r1 = Ss + ib * 68 + h * 32;
    const float wi0 = 1.0f - fi;
    // T via float4 LDS reads (9 loads/row instead of 33 conflicted scalars)
    float T[33];
    #pragma unroll
    for (int k4 = 0; k4 < 8; ++k4) {
      float4 a4 = *(const float4*)(r0 + 4 * k4);
      float4 b4 = *(const float4*)(r1 + 4 * k4);
      T[4 * k4 + 0] = wi0 * a4.x + fi * b4.x;
      T[4 * k4 + 1] = wi0 * a4.y + fi * b4.y;
      T[4 * k4 + 2] = wi0 * a4.z + fi * b4.z;
      T[4 * k4 + 3] = wi0 * a4.w + fi * b4.w;
    }
    T[32] = wi0 * r0[32] + fi * r1[32];
    float mx = T[0];
    #pragma unroll
    for (int k = 1; k < 33; ++k) mx = fmaxf(mx, T[k]);
    mx = fmaxf(mx, __shfl_xor(mx, 1));   // max over T >= max over S128 row (convex combos)
    float p[33];
    #pragma unroll
    for (int k = 0; k < 33; ++k) p[k] = 0.f;
    float sum = 0.f;
    if (h == 0) {
      #pragma unroll
      for (int j = 0; j < 64; ++j) {
        JTAP(j, ja, jb, fj);
        float v = (1.0f - fj) * T[ja] + fj * T[jb];
        float e = __expf(v - mx);
        sum += e;
        p[ja] += e * (1.0f - fj);
        p[jb] += e * fj;
      }
    } else {
      #pragma unroll
      for (int j = 64; j < 128; ++j) {
        JTAP(j, ja, jb, fj);
        float v = (1.0f - fj) * T[ja - 32] + fj * T[jb - 32];
        float e = __expf(v - mx);
        sum += e;
        p[ja - 32] += e * (1.0f - fj);
        p[jb - 32] += e * fj;
      }
    }
    sum += __shfl_xor(sum, 1);
    float other = __shfl_xor(h ? p[0] : p[32], 1);
    __syncthreads();   // all Ss reads complete before Pw overwrites the same LDS
    __half* prow = &PwsH[i * 66];
    if (h == 0) {
      p[32] += other;
      #pragma unroll
      for (int k = 0; k < 33; ++k) prow[k] = __float2half(p[k]);
      Pinvs[i] = 1.0f / sum;
    } else {
      p[0] += other;
      #pragma unroll
      for (int k = 0; k < 33; ++k) prow[32 + k] = __float2half(p[k]);
      prow[65] = __float2half(0.f);
    }
  }
  __syncthreads();

  // phase 4: dot2 contraction over 33 a-pairs; 2-chain ILP; wave-coalesced veA
  {
    const int i = t & 127;
    const int cg = t >> 7;
    const float inv = Pinvs[i];
    hf2 pw[33];
    const hf2* prow2 = (const hf2*)&PwsH[i * 66];
    #pragma unroll
    for (int ap = 0; ap < 33; ++ap) pw[ap] = prow2[ap];
    #pragma unroll
    for (int l = 0; l < 8; ++l) {
      const int c = cg * 8 + l;
      const hf2* vr = (const hf2*)&vasH[c * 66];
      const hf2* vp = (const hf2*)veA + (size_t)(c * 33) * 128 + i;
      float sv0 = 0.f, sv1 = 0.f, se0 = 0.f, se1 = 0.f;
      #pragma unroll
      for (int ap = 0; ap < 32; ap += 2) {
        sv0 = FDOT2(vr[ap], pw[ap], sv0);
        sv1 = FDOT2(vr[ap + 1], pw[ap + 1], sv1);
        se0 = FDOT2(vp[(size_t)ap * 128], pw[ap], se0);
        se1 = FDOT2(vp[(size_t)(ap + 1) * 128], pw[ap + 1], se1);
      }
      sv0 = FDOT2(vr[32], pw[32], sv0);
      se0 = FDOT2(vp[(size_t)32 * 128], pw[32], se0);
      float sv = sv0 + sv1, se = se0 + se1;
      int c2 = g * 16 + c;
      int o0 = 2 * c2;
      float val = og[o0] * RSBN * (sv * inv) + ob[o0]
                + og[o0 + 1] * RSBN * (se * inv) + ob[o0 + 1];
      yT[((size_t)(n * 128 + c2)) * 16384 + w * 128 + i] = val;
    }
  }
}

// ---------- XS: stage yT plane (fp32 LDS), emit xnb (shift+IN, bf16) + yStd (fp32) ----------
// grid 316: blocks 0..255 = (n, output cx); 256..315 = (n, ch 10..39) yStd-only.
__global__ __launch_bounds__(256) void k_xs(const float* __restrict__ yT,
                                            const float* __restrict__ inw,
                                            const float* __restrict__ inb,
                                            short* __restrict__ xnb,
                                            float* __restrict__ yStd) {
  int gid = blockIdx.x;
  int n, cs, cx = -1;
  bool wStd;
  if (gid < 256) {
    n = gid >> 7; cx = gid & 127;
    cs = (cx < 40) ? (cx % 10) : cx;
    wStd = (cx < 10) || (cx >= 40);
  } else {
    int u = gid - 256;
    n = u / 30; cs = 10 + (u % 30);
    wStd = true;
  }
  int dh = 0, dw = 0;
  if (cx >= 0) {
    if (cx < 10)       dw = -2;
    else if (cx < 20)  dw = 2;
    else if (cx < 30)  dh = -2;
    else if (cx < 40)  dh = 2;
  }
  __shared__ float Sb[128 * 130];   // [w][i], stride 130 floats
  __shared__ float sm[8];
  const float* src = yT + ((size_t)(n * 128 + cs)) * 16384;
  int t = threadIdx.x;
  #pragma unroll
  for (int l = 0; l < 16; ++l) {
    int q = t + l * 256;
    float4 v = *(const float4*)&src[q * 4];    // 4 consecutive i, fixed w
    int w = q >> 5, i0 = (q * 4) & 127;
    float* d = &Sb[w * 130 + i0];
    *(float2*)d = make_float2(v.x, v.y);
    *(float2*)(d + 2) = make_float2(v.z, v.w);
  }
  __syncthreads();
  if (wStd) {   // exact fp32 pass-through, standard (i,w) order
    float* dst = yStd + ((size_t)(n * 128 + cs)) * 16384;
    for (int l = 0; l < 64; ++l) {
      int idx = t + l * 256;
      int h = idx >> 7, w = idx & 127;
      dst[idx] = Sb[w * 130 + h];
    }
  }
  if (cx >= 0) {
    float s = 0.f, q2 = 0.f;
    for (int l = 0; l < 64; ++l) {
      int idx = t + l * 256;
      int h = idx >> 7, w = idx & 127;
      int hs = h + dh, ws = w + dw;
      float v = (hs >= 0 && hs < 128 && ws >= 0 && ws < 128) ? Sb[ws * 130 + hs] : 0.f;
      s += v; q2 += v * v;
    }
    #pragma unroll
    for (int o = 32; o; o >>= 1) { s += __shfl_down(s, o); q2 += __shfl_down(q2, o); }
    if ((t & 63) == 0) { sm[(t >> 6) * 2] = s; sm[(t >> 6) * 2 + 1] = q2; }
    __syncthreads();
    float S_ = sm[0] + sm[2] + sm[4] + sm[6];
    float Q_ = sm[1] + sm[3] + sm[5] + sm[7];
    float mean = S_ * (1.0f / 16384.0f);
    float var = Q_ * (1.0f / 16384.0f) - mean * mean;
    float scale = inw[cx] * rsqrtf(var + 1e-5f);
    float shift = inb[cx] - mean * scale;
    short* dst = xnb + ((size_t)(n * 128 + cx)) * 16384;
    for (int l = 0; l < 64; ++l) {
      int idx = t + l * 256;
      int h = idx >> 7, w = idx & 127;
      int hs = h + dh, ws = w + dw;
      float v = (hs >= 0 && hs < 128 && ws >= 0 && ws < 128) ? Sb[ws * 130 + hs] : 0.f;
      dst[idx] = f2b(v * scale + shift);
    }
  }
}

// ---------- MFMA GEMM 2: h1 = gelu(W1 . xn) ----------
__global__ __launch_bounds__(256) void k_mlp1_mfma(
    const short* __restrict__ xnb, const short* __restrict__ w1b,
    short* __restrict__ h1) {
  const int ob = blockIdx.x * 128;
  const int pb = blockIdx.y * 128;
  const int n = blockIdx.z;
  __shared__ short Asm[128 * 40];
  __shared__ short Bsm[128 * 40];
  const int t = threadIdx.x;
  const int lane = t & 63, wv = t >> 6;
  const int wm = wv >> 1, wn = wv & 1;
  const int lr = lane & 15, lk = (lane >> 4) * 8;
  f32x4 acc[4][4];
  #pragma unroll
  for (int i = 0; i < 4; ++i)
    #pragma unroll
    for (int j = 0; j < 4; ++j)
      #pragma unroll
      for (int q = 0; q < 4; ++q) acc[i][j][q] = 0.f;
  const short* X = xnb + (size_t)n * 128 * 16384;
  for (int k0 = 0; k0 < 128; k0 += 32) {
    #pragma unroll
    for (int i2 = 0; i2 < 2; ++i2) {
      int u = t + 256 * i2;
      int row = u >> 2, kq = (u & 3) * 8;
      *(bf16x8*)&Asm[row * 40 + kq] = *(const bf16x8*)&w1b[(ob + row) * 128 + k0 + kq];
    }
    #pragma unroll
    for (int i2 = 0; i2 < 2; ++i2) {
      int u = t + 256 * i2;
      int k = u >> 4, p8 = (u & 15) * 8;
      bf16x8 hv = *(const bf16x8*)&X[(size_t)(k0 + k) * 16384 + pb + p8];
      #pragma unroll
      for (int j = 0; j < 8; ++j) Bsm[(p8 + j) * 40 + k] = hv[j];
    }
    __syncthreads();
    bf16x8 af[4], bfr[4];
    #pragma unroll
    for (int mf = 0; mf < 4; ++mf) af[mf] = *(bf16x8*)&Asm[(wm * 64 + mf * 16 + lr) * 40 + lk];
    #pragma unroll
    for (int nf = 0; nf < 4; ++nf) bfr[nf] = *(bf16x8*)&Bsm[(wn * 64 + nf * 16 + lr) * 40 + lk];
    #pragma unroll
    for (int mf = 0; mf < 4; ++mf)
      #pragma unroll
      for (int nf = 0; nf < 4; ++nf)
        acc[mf][nf] = MFMA16(af[mf], bfr[nf], acc[mf][nf]);
    __syncthreads();
  }
  #pragma unroll
  for (int mf = 0; mf < 4; ++mf)
    #pragma unroll
    for (int r = 0; r < 4; ++r) {
      int o = ob + wm * 64 + mf * 16 + (lane >> 4) * 4 + r;
      #pragma unroll
      for (int nf = 0; nf < 4; ++nf) {
        int p = pb + wn * 64 + nf * 16 + lr;
        h1[((size_t)(n * 512 + o)) * 16384 + p] = f2b(gelu_exact(acc[mf][nf][r]));
      }
    }
}

// ---------- MFMA GEMM 3: out = W2 . h1 + identity(yStd) ----------
__global__ __launch_bounds__(256) void k_mlp2_mfma(
    const short* __restrict__ h1, const short* __restrict__ w2b,
    const float* __restrict__ y, float* __restrict__ out) {
  const int pb = blockIdx.x * 128;
  const int ob = blockIdx.y * 128;
  const int n = blockIdx.z;
  __shared__ short Asm[128 * 40];
  __shared__ short Bsm[128 * 40];
  const int t = threadIdx.x;
  const int lane = t & 63, wv = t >> 6;
  const int wm = wv >> 1, wn = wv & 1;
  const int lr = lane & 15, lk = (lane >> 4) * 8;
  f32x4 acc[4][4];
  #pragma unroll
  for (int i = 0; i < 4; ++i)
    #pragma unroll
    for (int j = 0; j < 4; ++j)
      #pragma unroll
      for (int q = 0; q < 4; ++q) acc[i][j][q] = 0.f;
  const short* H = h1 + (size_t)n * 512 * 16384;
  for (int k0 = 0; k0 < 512; k0 += 32) {
    #pragma unroll
    for (int i2 = 0; i2 < 2; ++i2) {
      int u = t + 256 * i2;
      int row = u >> 2, kq = (u & 3) * 8;
      *(bf16x8*)&Asm[row * 40 + kq] = *(const bf16x8*)&w2b[(ob + row) * 512 + k0 + kq];
    }
    #pragma unroll
    for (int i2 = 0; i2 < 2; ++i2) {
      int u = t + 256 * i2;
      int k = u >> 4, p8 = (u & 15) * 8;
      bf16x8 hv = *(const bf16x8*)&H[(size_t)(k0 + k) * 16384 + pb + p8];
      #pragma unroll
      for (int j = 0; j < 8; ++j) Bsm[(p8 + j) * 40 + k] = hv[j];
    }
    __syncthreads();
    bf16x8 af[4], bfr[4];
    #pragma unroll
    for (int mf = 0; mf < 4; ++mf) af[mf] = *(bf16x8*)&Asm[(wm * 64 + mf * 16 + lr) * 40 + lk];
    #pragma unroll
    for (int nf = 0; nf < 4; ++nf) bfr[nf] = *(bf16x8*)&Bsm[(wn * 64 + nf * 16 + lr) * 40 + lk];
    #pragma unroll
    for (int mf = 0; mf < 4; ++mf)
      #pragma unroll
      for (int nf = 0; nf < 4; ++nf)
        acc[mf][nf] = MFMA16(af[mf], bfr[nf], acc[mf][nf]);
    __syncthreads();
  }
  #pragma unroll
  for (int mf = 0; mf < 4; ++mf)
    #pragma unroll
    for (int r = 0; r < 4; ++r) {
      int o = ob + wm * 64 + mf * 16 + (lane >> 4) * 4 + r;
      #pragma unroll
      for (int nf = 0; nf < 4; ++nf) {
        int p = pb + wn * 64 + nf * 16 + lr;
        size_t base = ((size_t)(n * 128 + o)) * 16384 + p;
        out[base] = acc[mf][nf][r] + y[base];
      }
    }
}

extern "C" void kernel_launch(void* const* d_in, const int* in_sizes, int n_in,
                              void* d_out, int out_size, void* d_ws, size_t ws_size,
                              hipStream_t stream) {
  const float* x        = (const float*)d_in[0];
  const float* w_qkv    = (const float*)d_in[1];
  const float* bn_qkv_g = (const float*)d_in[2];
  const float* bn_qkv_b = (const float*)d_in[3];
  const float* bn_sim_g = (const float*)d_in[4];
  const float* bn_sim_b = (const float*)d_in[5];
  const float* bn_out_g = (const float*)d_in[6];
  const float* bn_out_b = (const float*)d_in[7];
  const float* in_w     = (const float*)d_in[8];
  const float* in_b     = (const float*)d_in[9];
  const float* mlp_w1   = (const float*)d_in[10];
  const float* mlp_w2   = (const float*)d_in[11];
  const float* base_rel = (const float*)d_in[12];
  float* Wp = (float*)d_ws;

  float* relAp  = Wp + 0;            // 35,456
  float* relATp = Wp + 35456;        // 35,456
  __half* veA   = (__half*)(Wp + 70912);     // 135,168 halves (67,584 f)
  float* yT     = Wp + 138496;       // 4,194,304
  float* yStd   = Wp + 4332800;      // 4,194,304
  short* wqb    = (short*)(Wp + 8527104);    // 32,768 shorts
  short* w1b    = (short*)(Wp + 8543488);    // 65,536 shorts
  short* w2b    = (short*)(Wp + 8576256);    // 65,536 shorts
  short* xnb    = (short*)(Wp + 8609024);    // 4,194,304 shorts
  short* xab    = (short*)(Wp + 10706176);   // 2,129,920 shorts (dead after qkv)
  short* qkva   = (short*)(Wp + 11771136);   // 4,259,840 shorts (dead after attn)
  short* h1b    = (short*)(Wp + 10706176);   // 16,777,216 shorts (overlays xab+qkva)
  // peak: 19,094,784 floats = 76.4 MB

  k_prep<<<dim3(1049), dim3(256), 0, stream>>>(base_rel, w_qkv, mlp_w1, mlp_w2,
                                               wqb, w1b, w2b, relAp, relATp, veA);
  k_xa<<<dim3(8320), dim3(256), 0, stream>>>(x, xab);
  k_qkv_mfma<<<dim3(2, 65, 2), dim3(256), 0, stream>>>(xab, wqb, bn_qkv_g, bn_qkv_b, qkva);
  k_attn<<<dim3(2048), dim3(256), 0, stream>>>(qkva, relAp, relATp, veA,
                                               bn_sim_g, bn_sim_b, bn_out_g, bn_out_b, yT);
  k_xs<<<dim3(316), dim3(256), 0, stream>>>(yT, in_w, in_b, xnb, yStd);
  k_mlp1_mfma<<<dim3(4, 128, 2), dim3(256), 0, stream>>>(xnb, w1b, h1b);
  k_mlp2_mfma<<<dim3(128, 1, 2), dim3(256), 0, stream>>>(h1b, w2b, yStd, (float*)d_out);
}

// Round 14
// 161.280 us; speedup vs baseline: 1.5438x; 1.1167x over previous
//
#include <hip/hip_runtime.h>
#include <hip/hip_bf16.h>
#include <hip/hip_fp16.h>

#define GG 8
#define AA 65
#define BB 256

typedef __attribute__((ext_vector_type(8))) short bf16x8;
typedef __attribute__((ext_vector_type(4))) short s16x4;
typedef __attribute__((ext_vector_type(4))) float f32x4;
typedef _Float16 hf2 __attribute__((ext_vector_type(2)));
#define MFMA16(a, b, c) __builtin_amdgcn_mfma_f32_16x16x32_bf16(a, b, c, 0, 0, 0)
#define FDOT2(a, b, c) __builtin_amdgcn_fdot2((a), (b), (c), false)

__device__ __forceinline__ void rz_taps(int o, float scale, int in_size,
                                        int& ia, int& ib, float& f) {
  float pos = (o + 0.5f) * scale - 0.5f;
  float fl = floorf(pos);
  int i0 = (int)fl;
  f = pos - fl;
  ia = i0 < 0 ? 0 : i0;
  int i1 = i0 + 1;
  ib = i1 > (in_size - 1) ? (in_size - 1) : i1;
}

// Compile-time 128->65 tap: pos = (j+0.5)*65/128-0.5 = (130j-63)/256 exactly.
#define JTAP(jc, ja, jb, fj) \
  const int num_ = 130 * (jc) - 63;               \
  const int fl_ = num_ >> 8;                      \
  const int ja = fl_ < 0 ? 0 : fl_;               \
  const int jb = (fl_ + 1 > 64) ? 64 : (fl_ + 1); \
  const float fj = (float)(num_ - (fl_ << 8)) * 0.00390625f;

__device__ __forceinline__ float gelu_exact(float v) {
  return 0.5f * v * (1.0f + erff(v * 0.70710678118654752f));
}

__device__ __forceinline__ short f2b(float f) {
  __hip_bfloat16 h = __float2bfloat16(f);
  return *reinterpret_cast<short*>(&h);
}
__device__ __forceinline__ float b2f(short s) {
  unsigned int u = ((unsigned int)(unsigned short)s) << 16;
  return __uint_as_float(u);
}

#define RSBN 0.99999500003749977f  // 1/sqrt(1+1e-5)

// ---------- PREP: weights->bf16, relA2/relAT2 (fp16 c-pair packed), veA ----------
__global__ void k_prep(const float* __restrict__ base, const float* __restrict__ wq,
                       const float* __restrict__ w1, const float* __restrict__ w2,
                       short* __restrict__ wqb, short* __restrict__ w1b,
                       short* __restrict__ w2b, __half* __restrict__ relA2h,
                       __half* __restrict__ relAT2h, __half* __restrict__ veA) {
  int blk = blockIdx.x;
  int tt = threadIdx.x;
  if (blk < 256) {             // weights
    int i = blk * 256 + tt;
    if (i < 32768) wqb[i] = f2b(wq[i]);
    w1b[i] = f2b(w1[i]);
    w2b[i] = f2b(w2[i]);
    return;
  }
  blk -= 256;
  if (blk < 265) {             // q_emb / k_emb^T, fp16 c-pair dword layout [cp][i][68]
    int idx = blk * 256 + tt;
    if (idx >= 16 * AA * AA) return;
    int j = idx % AA;
    int r = idx / AA;
    int i = r % AA;
    int c = r / AA;
    int ia, ib, ja, jb; float fi, fj;
    rz_taps(i, 255.0f / 65.0f, 255, ia, ib, fi);
    rz_taps(j, 255.0f / 65.0f, 255, ja, jb, fj);
    const float* S = base + (size_t)c * 255 * 255;
    float v = (1.0f - fi) * ((1.0f - fj) * S[ia * 255 + ja] + fj * S[ia * 255 + jb])
            + fi * ((1.0f - fj) * S[ib * 255 + ja] + fj * S[ib * 255 + jb]);
    if (c < 8) {
      relA2h[((((c >> 1) * 4420) + i * 68 + j) << 1) + (c & 1)] = __float2half(v);
    } else {
      int c2 = c - 8;
      relAT2h[((((c2 >> 1) * 4420) + j * 68 + i) << 1) + (c2 & 1)] = __float2half(v);
    }
    return;
  }
  blk -= 265;
  {  // veA[c][ap][128i] half2 (wave-coalesced: i innermost): i-upsampled v_emb
    int idx = blk * 256 + tt;  // 16*66*128 = 135,168
    if (idx >= 16 * 66 * 128) return;
    int i = idx & 127;
    int r = idx >> 7;
    int a = r % 66, c = r / 66;
    float v = 0.f;
    if (a < 65) {
      int ia, ib; float fi;
      rz_taps(i, 65.0f / 128.0f, 65, ia, ib, fi);
      int ja, jb; float fj;
      rz_taps(a, 255.0f / 65.0f, 255, ja, jb, fj);
      int p0a, p0b; float g0;
      rz_taps(ia, 255.0f / 65.0f, 255, p0a, p0b, g0);
      int p1a, p1b; float g1;
      rz_taps(ib, 255.0f / 65.0f, 255, p1a, p1b, g1);
      const float* S = base + (size_t)(16 + c) * 255 * 255;
      float r0 = (1.0f - g0) * ((1.0f - fj) * S[p0a * 255 + ja] + fj * S[p0a * 255 + jb])
               + g0 * ((1.0f - fj) * S[p0b * 255 + ja] + fj * S[p0b * 255 + jb]);
      float r1 = (1.0f - g1) * ((1.0f - fj) * S[p1a * 255 + ja] + fj * S[p1a * 255 + jb])
               + g1 * ((1.0f - fj) * S[p1b * 255 + ja] + fj * S[p1b * 255 + jb]);
      v = (1.0f - fi) * r0 + fi * r1;
    }
    veA[((size_t)(c * 33 + (a >> 1)) * 128 + i) * 2 + (a & 1)] = __float2half(v);
  }
}

// ---------- MFMA GEMM 1: qkva[n][o][a][w] = bf16(BN(Wqkv . downsample_i(x))) ----------
// B-staging reads x rows ia/ib directly with the per-block a-tap (k_xa fused away).
__global__ __launch_bounds__(256) void k_qkv_mfma(
    const float* __restrict__ x, const short* __restrict__ wqb,
    const float* __restrict__ bg, const float* __restrict__ bb,
    short* __restrict__ out) {
  const int ob = blockIdx.x * 128;
  const int a = blockIdx.y;
  const int n = blockIdx.z;
  __shared__ short Asm[128 * 40];
  __shared__ short Bsm[128 * 40];
  const int t = threadIdx.x;
  const int lane = t & 63, wv = t >> 6;
  const int wm = wv >> 1, wn = wv & 1;
  const int lr = lane & 15, lk = (lane >> 4) * 8;
  int ia, ib; float f;
  rz_taps(a, 128.0f / 65.0f, 128, ia, ib, f);
  const float f0 = 1.0f - f;
  f32x4 acc[4][4];
  #pragma unroll
  for (int i = 0; i < 4; ++i)
    #pragma unroll
    for (int j = 0; j < 4; ++j)
      #pragma unroll
      for (int q = 0; q < 4; ++q) acc[i][j][q] = 0.f;
  const float* X = x + (size_t)n * 128 * 16384;
  for (int k0 = 0; k0 < 128; k0 += 32) {
    #pragma unroll
    for (int i2 = 0; i2 < 2; ++i2) {
      int u = t + 256 * i2;
      int row = u >> 2, kq = (u & 3) * 8;
      *(bf16x8*)&Asm[row * 40 + kq] = *(const bf16x8*)&wqb[(ob + row) * 128 + k0 + kq];
    }
    #pragma unroll
    for (int i2 = 0; i2 < 2; ++i2) {
      int u = t + 256 * i2;
      int k = u >> 4, p8 = (u & 15) * 8;
      int c = k0 + k;
      const float* rowA = X + ((size_t)c * 128 + ia) * 128 + p8;
      const float* rowB = X + ((size_t)c * 128 + ib) * 128 + p8;
      float4 a0 = *(const float4*)rowA;
      float4 a1 = *(const float4*)(rowA + 4);
      float4 b0 = *(const float4*)rowB;
      float4 b1 = *(const float4*)(rowB + 4);
      short* d = &Bsm[p8 * 40 + k];
      d[0 * 40] = f2b(f0 * a0.x + f * b0.x);
      d[1 * 40] = f2b(f0 * a0.y + f * b0.y);
      d[2 * 40] = f2b(f0 * a0.z + f * b0.z);
      d[3 * 40] = f2b(f0 * a0.w + f * b0.w);
      d[4 * 40] = f2b(f0 * a1.x + f * b1.x);
      d[5 * 40] = f2b(f0 * a1.y + f * b1.y);
      d[6 * 40] = f2b(f0 * a1.z + f * b1.z);
      d[7 * 40] = f2b(f0 * a1.w + f * b1.w);
    }
    __syncthreads();
    bf16x8 af[4], bfr[4];
    #pragma unroll
    for (int mf = 0; mf < 4; ++mf) af[mf] = *(bf16x8*)&Asm[(wm * 64 + mf * 16 + lr) * 40 + lk];
    #pragma unroll
    for (int nf = 0; nf < 4; ++nf) bfr[nf] = *(bf16x8*)&Bsm[(wn * 64 + nf * 16 + lr) * 40 + lk];
    #pragma unroll
    for (int mf = 0; mf < 4; ++mf)
      #pragma unroll
      for (int nf = 0; nf < 4; ++nf)
        acc[mf][nf] = MFMA16(af[mf], bfr[nf], acc[mf][nf]);
    __syncthreads();
  }
  #pragma unroll
  for (int mf = 0; mf < 4; ++mf) {
    #pragma unroll
    for (int r = 0; r < 4; ++r) {
      int o = ob + wm * 64 + mf * 16 + (lane >> 4) * 4 + r;
      float sc = bg[o] * RSBN, sh = bb[o];
      #pragma unroll
      for (int nf = 0; nf < 4; ++nf) {
        int p = wn * 64 + nf * 16 + lr;
        out[((size_t)(n * 256 + o) * 65 + a) * 128 + p] = f2b(acc[mf][nf][r] * sc + sh);
      }
    }
  }
}

// ---------- F: fused sim(fp16 dot2) + softmax + dot2 sv/sve + bn_out ----------
__global__ void k_attn(const short* __restrict__ qkva, const __half* __restrict__ relA2,
                       const __half* __restrict__ relAT2, const __half* __restrict__ veA,
                       const float* __restrict__ sg, const float* __restrict__ sb,
                       const float* __restrict__ og, const float* __restrict__ ob,
                       float* __restrict__ yT) {
  int orig = blockIdx.x;
  int bg = ((orig & 7) << 8) + (orig >> 3);  // bijective XCD-chunk swizzle
  int b = bg >> 3, g = bg & 7;
  int n = b >> 7, w = b & 127;
  __shared__ float Ss[65 * 68];          // 17,680 B; reused as PwsH after sync
  __shared__ float u0[536];              // 2,144 B: qs2(260dw)+ks2(272dw); vasH after
  __shared__ float Pinvs[128];           // 512 B -> 20,336 B total
  __half* PwsH = (__half*)Ss;
  hf2* qs2 = (hf2*)u0;
  hf2* ks2v = (hf2*)(u0 + 260);
  float* ks2f = u0 + 260;
  __half* vasH = (__half*)u0;
  int t = threadIdx.x;
  const short* Qbase = qkva + ((size_t)(n * 256 + g * 32) * 65) * 128 + w;

  // phase 1: stage q,k as fp16 c-pairs (bf16 -> fp16 exact for these magnitudes)
  for (int l = t; l < 520; l += 256) {
    int isQ = (l < 260);
    int u2 = isQ ? l : l - 260;
    int cp = u2 / 65, a = u2 - cp * 65;
    int cbase = (cp << 1) + (isQ ? 0 : 8);
    float v0 = b2f(Qbase[(size_t)(cbase * 65 + a) * 128]);
    float v1 = b2f(Qbase[(size_t)((cbase + 1) * 65 + a) * 128]);
    hf2 h;
    h[0] = (_Float16)v0;
    h[1] = (_Float16)v1;
    if (isQ) qs2[cp * 65 + a] = h;
    else ks2v[cp * 68 + a] = h;
  }
  __syncthreads();

  // phase 2: sim 65x65 via packed fdot2 (qk+qr+kr, BN-combined)
  {
    float sqk = sg[g] * RSBN, sqr = sg[8 + g] * RSBN, skr = sg[16 + g] * RSBN;
    float badd = sb[g] + sb[8 + g] + sb[16 + g];
    const float* rAf = (const float*)relA2;
    const float* rTf = (const float*)relAT2;
    const hf2* rAv = (const hf2*)relA2;
    const hf2* rTv = (const hf2*)relAT2;
    for (int u = t; u < 65 * 17; u += 256) {
      int i = u / 17, jq = u - i * 17;
      hf2 q2[4];
      #pragma unroll
      for (int cp = 0; cp < 4; ++cp) q2[cp] = qs2[cp * 65 + i];
      if (jq < 16) {
        int j0 = jq * 4;
        int lofs = i * 68 + j0;
        float qk0 = 0, qk1 = 0, qk2 = 0, qk3 = 0;
        float qr0 = 0, qr1 = 0, qr2 = 0, qr3 = 0;
        float kr0 = 0, kr1 = 0, kr2 = 0, kr3 = 0;
        #pragma unroll
        for (int cp = 0; cp < 4; ++cp) {
          float4 kq = *(const float4*)&ks2f[cp * 68 + j0];
          float4 ra = *(const float4*)&rAf[cp * 4420 + lofs];
          float4 rt = *(const float4*)&rTf[cp * 4420 + lofs];
          hf2 k0 = __builtin_bit_cast(hf2, kq.x);
          hf2 k1 = __builtin_bit_cast(hf2, kq.y);
          hf2 k2h = __builtin_bit_cast(hf2, kq.z);
          hf2 k3 = __builtin_bit_cast(hf2, kq.w);
          qk0 = FDOT2(k0, q2[cp], qk0);
          qk1 = FDOT2(k1, q2[cp], qk1);
          qk2 = FDOT2(k2h, q2[cp], qk2);
          qk3 = FDOT2(k3, q2[cp], qk3);
          qr0 = FDOT2(__builtin_bit_cast(hf2, ra.x), q2[cp], qr0);
          qr1 = FDOT2(__builtin_bit_cast(hf2, ra.y), q2[cp], qr1);
          qr2 = FDOT2(__builtin_bit_cast(hf2, ra.z), q2[cp], qr2);
          qr3 = FDOT2(__builtin_bit_cast(hf2, ra.w), q2[cp], qr3);
          kr0 = FDOT2(__builtin_bit_cast(hf2, rt.x), k0, kr0);
          kr1 = FDOT2(__builtin_bit_cast(hf2, rt.y), k1, kr1);
          kr2 = FDOT2(__builtin_bit_cast(hf2, rt.z), k2h, kr2);
          kr3 = FDOT2(__builtin_bit_cast(hf2, rt.w), k3, kr3);
        }
        float4 res;
        res.x = sqk * qk0 + sqr * qr0 + skr * kr0 + badd;
        res.y = sqk * qk1 + sqr * qr1 + skr * kr1 + badd;
        res.z = sqk * qk2 + sqr * qr2 + skr * kr2 + badd;
        res.w = sqk * qk3 + sqr * qr3 + skr * kr3 + badd;
        *(float4*)&Ss[lofs] = res;
      } else {
        int lofs = i * 68 + 64;
        float qk = 0, qr = 0, kr = 0;
        #pragma unroll
        for (int cp = 0; cp < 4; ++cp) {
          hf2 kv = ks2v[cp * 68 + 64];
          qk = FDOT2(kv, q2[cp], qk);
          qr = FDOT2(rAv[cp * 4420 + lofs], q2[cp], qr);
          kr = FDOT2(rTv[cp * 4420 + lofs], kv, kr);
        }
        Ss[lofs] = sqk * qk + sqr * qr + skr * kr + badd;
      }
    }
  }
  __syncthreads();

  // phase 3: v stage (overlays u0) + register-T softmax fold (r13 structure)
  for (int l = t; l < 16 * 66; l += 256) {
    int c = l / 66, a = l - c * 66;
    float v = (a < 65) ? b2f(Qbase[(size_t)((16 + c) * 65 + a) * 128]) : 0.f;
    vasH[l] = __float2half(v);
  }
  {
    const int i = t >> 1, h = t & 1;
    int ia, ib; float fi;
    rz_taps(i, 65.0f / 128.0f, 65, ia, ib, fi);
    const float* r0 = Ss + ia * 68 + h * 32;
    const float* r1 = Ss + ib * 68 + h * 32;
    const float wi0 = 1.0f - fi;
    float T[33];
    #pragma unroll
    for (int k4 = 0; k4 < 8; ++k4) {
      float4 a4 = *(const float4*)(r0 + 4 * k4);
      float4 b4 = *(const float4*)(r1 + 4 * k4);
      T[4 * k4 + 0] = wi0 * a4.x + fi * b4.x;
      T[4 * k4 + 1] = wi0 * a4.y + fi * b4.y;
      T[4 * k4 + 2] = wi0 * a4.z + fi * b4.z;
      T[4 * k4 + 3] = wi0 * a4.w + fi * b4.w;
    }
    T[32] = wi0 * r0[32] + fi * r1[32];
    float mx = T[0];
    #pragma unroll
    for (int k = 1; k < 33; ++k) mx = fmaxf(mx, T[k]);
    mx = fmaxf(mx, __shfl_xor(mx, 1));
    float p[33];
    #pragma unroll
    for (int k = 0; k < 33; ++k) p[k] = 0.f;
    float sum = 0.f;
    if (h == 0) {
      #pragma unroll
      for (int j = 0; j < 64; ++j) {
        JTAP(j, ja, jb, fj);
        float v = (1.0f - fj) * T[ja] + fj * T[jb];
        float e = __expf(v - mx);
        sum += e;
        p[ja] += e * (1.0f - fj);
        p[jb] += e * fj;
      }
    } else {
      #pragma unroll
      for (int j = 64; j < 128; ++j) {
        JTAP(j, ja, jb, fj);
        float v = (1.0f - fj) * T[ja - 32] + fj * T[jb - 32];
        float e = __expf(v - mx);
        sum += e;
        p[ja - 32] += e * (1.0f - fj);
        p[jb - 32] += e * fj;
      }
    }
    sum += __shfl_xor(sum, 1);
    float other = __shfl_xor(h ? p[0] : p[32], 1);
    __syncthreads();   // all Ss reads complete before Pw overwrites the same LDS
    __half* prow = &PwsH[i * 66];
    if (h == 0) {
      p[32] += other;
      #pragma unroll
      for (int k = 0; k < 33; ++k) prow[k] = __float2half(p[k]);
      Pinvs[i] = 1.0f / sum;
    } else {
      p[0] += other;
      #pragma unroll
      for (int k = 0; k < 33; ++k) prow[32 + k] = __float2half(p[k]);
      prow[65] = __float2half(0.f);
    }
  }
  __syncthreads();

  // phase 4: dot2 contraction over 33 a-pairs; 2-chain ILP; wave-coalesced veA
  {
    const int i = t & 127;
    const int cg = t >> 7;
    const float inv = Pinvs[i];
    hf2 pw[33];
    const hf2* prow2 = (const hf2*)&PwsH[i * 66];
    #pragma unroll
    for (int ap = 0; ap < 33; ++ap) pw[ap] = prow2[ap];
    #pragma unroll
    for (int l = 0; l < 8; ++l) {
      const int c = cg * 8 + l;
      const hf2* vr = (const hf2*)&vasH[c * 66];
      const hf2* vp = (const hf2*)veA + (size_t)(c * 33) * 128 + i;
      float sv0 = 0.f, sv1 = 0.f, se0 = 0.f, se1 = 0.f;
      #pragma unroll
      for (int ap = 0; ap < 32; ap += 2) {
        sv0 = FDOT2(vr[ap], pw[ap], sv0);
        sv1 = FDOT2(vr[ap + 1], pw[ap + 1], sv1);
        se0 = FDOT2(vp[(size_t)ap * 128], pw[ap], se0);
        se1 = FDOT2(vp[(size_t)(ap + 1) * 128], pw[ap + 1], se1);
      }
      sv0 = FDOT2(vr[32], pw[32], sv0);
      se0 = FDOT2(vp[(size_t)32 * 128], pw[32], se0);
      float sv = sv0 + sv1, se = se0 + se1;
      int c2 = g * 16 + c;
      int o0 = 2 * c2;
      float val = og[o0] * RSBN * (sv * inv) + ob[o0]
                + og[o0 + 1] * RSBN * (se * inv) + ob[o0 + 1];
      yT[((size_t)(n * 128 + c2)) * 16384 + w * 128 + i] = val;
    }
  }
}

// ---------- XS: stage yT plane (fp32 LDS), emit xnb (shift+IN, bf16) + yStd (fp32) ----------
__global__ __launch_bounds__(256) void k_xs(const float* __restrict__ yT,
                                            const float* __restrict__ inw,
                                            const float* __restrict__ inb,
                                            short* __restrict__ xnb,
                                            float* __restrict__ yStd) {
  int gid = blockIdx.x;
  int n, cs, cx = -1;
  bool wStd;
  if (gid < 256) {
    n = gid >> 7; cx = gid & 127;
    cs = (cx < 40) ? (cx % 10) : cx;
    wStd = (cx < 10) || (cx >= 40);
  } else {
    int u = gid - 256;
    n = u / 30; cs = 10 + (u % 30);
    wStd = true;
  }
  int dh = 0, dw = 0;
  if (cx >= 0) {
    if (cx < 10)       dw = -2;
    else if (cx < 20)  dw = 2;
    else if (cx < 30)  dh = -2;
    else if (cx < 40)  dh = 2;
  }
  __shared__ float Sb[128 * 130];
  __shared__ float sm[8];
  const float* src = yT + ((size_t)(n * 128 + cs)) * 16384;
  int t = threadIdx.x;
  #pragma unroll
  for (int l = 0; l < 16; ++l) {
    int q = t + l * 256;
    float4 v = *(const float4*)&src[q * 4];
    int w = q >> 5, i0 = (q * 4) & 127;
    float* d = &Sb[w * 130 + i0];
    *(float2*)d = make_float2(v.x, v.y);
    *(float2*)(d + 2) = make_float2(v.z, v.w);
  }
  __syncthreads();
  if (wStd) {
    float* dst = yStd + ((size_t)(n * 128 + cs)) * 16384;
    for (int l = 0; l < 64; ++l) {
      int idx = t + l * 256;
      int h = idx >> 7, w = idx & 127;
      dst[idx] = Sb[w * 130 + h];
    }
  }
  if (cx >= 0) {
    float s = 0.f, q2 = 0.f;
    for (int l = 0; l < 64; ++l) {
      int idx = t + l * 256;
      int h = idx >> 7, w = idx & 127;
      int hs = h + dh, ws = w + dw;
      float v = (hs >= 0 && hs < 128 && ws >= 0 && ws < 128) ? Sb[ws * 130 + hs] : 0.f;
      s += v; q2 += v * v;
    }
    #pragma unroll
    for (int o = 32; o; o >>= 1) { s += __shfl_down(s, o); q2 += __shfl_down(q2, o); }
    if ((t & 63) == 0) { sm[(t >> 6) * 2] = s; sm[(t >> 6) * 2 + 1] = q2; }
    __syncthreads();
    float S_ = sm[0] + sm[2] + sm[4] + sm[6];
    float Q_ = sm[1] + sm[3] + sm[5] + sm[7];
    float mean = S_ * (1.0f / 16384.0f);
    float var = Q_ * (1.0f / 16384.0f) - mean * mean;
    float scale = inw[cx] * rsqrtf(var + 1e-5f);
    float shift = inb[cx] - mean * scale;
    short* dst = xnb + ((size_t)(n * 128 + cx)) * 16384;
    for (int l = 0; l < 64; ++l) {
      int idx = t + l * 256;
      int h = idx >> 7, w = idx & 127;
      int hs = h + dh, ws = w + dw;
      float v = (hs >= 0 && hs < 128 && ws >= 0 && ws < 128) ? Sb[ws * 130 + hs] : 0.f;
      dst[idx] = f2b(v * scale + shift);
    }
  }
}

// ---------- MFMA GEMM 2: h1 = gelu(W1 . xn) ----------
__global__ __launch_bounds__(256) void k_mlp1_mfma(
    const short* __restrict__ xnb, const short* __restrict__ w1b,
    short* __restrict__ h1) {
  const int ob = blockIdx.x * 128;
  const int pb = blockIdx.y * 128;
  const int n = blockIdx.z;
  __shared__ short Asm[128 * 40];
  __shared__ short Bsm[128 * 40];
  const int t = threadIdx.x;
  const int lane = t & 63, wv = t >> 6;
  const int wm = wv >> 1, wn = wv & 1;
  const int lr = lane & 15, lk = (lane >> 4) * 8;
  f32x4 acc[4][4];
  #pragma unroll
  for (int i = 0; i < 4; ++i)
    #pragma unroll
    for (int j = 0; j < 4; ++j)
      #pragma unroll
      for (int q = 0; q < 4; ++q) acc[i][j][q] = 0.f;
  const short* X = xnb + (size_t)n * 128 * 16384;
  for (int k0 = 0; k0 < 128; k0 += 32) {
    #pragma unroll
    for (int i2 = 0; i2 < 2; ++i2) {
      int u = t + 256 * i2;
      int row = u >> 2, kq = (u & 3) * 8;
      *(bf16x8*)&Asm[row * 40 + kq] = *(const bf16x8*)&w1b[(ob + row) * 128 + k0 + kq];
    }
    #pragma unroll
    for (int i2 = 0; i2 < 2; ++i2) {
      int u = t + 256 * i2;
      int k = u >> 4, p8 = (u & 15) * 8;
      bf16x8 hv = *(const bf16x8*)&X[(size_t)(k0 + k) * 16384 + pb + p8];
      #pragma unroll
      for (int j = 0; j < 8; ++j) Bsm[(p8 + j) * 40 + k] = hv[j];
    }
    __syncthreads();
    bf16x8 af[4], bfr[4];
    #pragma unroll
    for (int mf = 0; mf < 4; ++mf) af[mf] = *(bf16x8*)&Asm[(wm * 64 + mf * 16 + lr) * 40 + lk];
    #pragma unroll
    for (int nf = 0; nf < 4; ++nf) bfr[nf] = *(bf16x8*)&Bsm[(wn * 64 + nf * 16 + lr) * 40 + lk];
    #pragma unroll
    for (int mf = 0; mf < 4; ++mf)
      #pragma unroll
      for (int nf = 0; nf < 4; ++nf)
        acc[mf][nf] = MFMA16(af[mf], bfr[nf], acc[mf][nf]);
    __syncthreads();
  }
  #pragma unroll
  for (int mf = 0; mf < 4; ++mf)
    #pragma unroll
    for (int r = 0; r < 4; ++r) {
      int o = ob + wm * 64 + mf * 16 + (lane >> 4) * 4 + r;
      #pragma unroll
      for (int nf = 0; nf < 4; ++nf) {
        int p = pb + wn * 64 + nf * 16 + lr;
        h1[((size_t)(n * 512 + o)) * 16384 + p] = f2b(gelu_exact(acc[mf][nf][r]));
      }
    }
}

// ---------- MFMA GEMM 3: out = W2 . h1 + identity(yStd) ----------
__global__ __launch_bounds__(256) void k_mlp2_mfma(
    const short* __restrict__ h1, const short* __restrict__ w2b,
    const float* __restrict__ y, float* __restrict__ out) {
  const int pb = blockIdx.x * 128;
  const int ob = blockIdx.y * 128;
  const int n = blockIdx.z;
  __shared__ short Asm[128 * 40];
  __shared__ short Bsm[128 * 40];
  const int t = threadIdx.x;
  const int lane = t & 63, wv = t >> 6;
  const int wm = wv >> 1, wn = wv & 1;
  const int lr = lane & 15, lk = (lane >> 4) * 8;
  f32x4 acc[4][4];
  #pragma unroll
  for (int i = 0; i < 4; ++i)
    #pragma unroll
    for (int j = 0; j < 4; ++j)
      #pragma unroll
      for (int q = 0; q < 4; ++q) acc[i][j][q] = 0.f;
  const short* H = h1 + (size_t)n * 512 * 16384;
  for (int k0 = 0; k0 < 512; k0 += 32) {
    #pragma unroll
    for (int i2 = 0; i2 < 2; ++i2) {
      int u = t + 256 * i2;
      int row = u >> 2, kq = (u & 3) * 8;
      *(bf16x8*)&Asm[row * 40 + kq] = *(const bf16x8*)&w2b[(ob + row) * 512 + k0 + kq];
    }
    #pragma unroll
    for (int i2 = 0; i2 < 2; ++i2) {
      int u = t + 256 * i2;
      int k = u >> 4, p8 = (u & 15) * 8;
      bf16x8 hv = *(const bf16x8*)&H[(size_t)(k0 + k) * 16384 + pb + p8];
      #pragma unroll
      for (int j = 0; j < 8; ++j) Bsm[(p8 + j) * 40 + k] = hv[j];
    }
    __syncthreads();
    bf16x8 af[4], bfr[4];
    #pragma unroll
    for (int mf = 0; mf < 4; ++mf) af[mf] = *(bf16x8*)&Asm[(wm * 64 + mf * 16 + lr) * 40 + lk];
    #pragma unroll
    for (int nf = 0; nf < 4; ++nf) bfr[nf] = *(bf16x8*)&Bsm[(wn * 64 + nf * 16 + lr) * 40 + lk];
    #pragma unroll
    for (int mf = 0; mf < 4; ++mf)
      #pragma unroll
      for (int nf = 0; nf < 4; ++nf)
        acc[mf][nf] = MFMA16(af[mf], bfr[nf], acc[mf][nf]);
    __syncthreads();
  }
  #pragma unroll
  for (int mf = 0; mf < 4; ++mf)
    #pragma unroll
    for (int r = 0; r < 4; ++r) {
      int o = ob + wm * 64 + mf * 16 + (lane >> 4) * 4 + r;
      #pragma unroll
      for (int nf = 0; nf < 4; ++nf) {
        int p = pb + wn * 64 + nf * 16 + lr;
        size_t base = ((size_t)(n * 128 + o)) * 16384 + p;
        out[base] = acc[mf][nf][r] + y[base];
      }
    }
}

extern "C" void kernel_launch(void* const* d_in, const int* in_sizes, int n_in,
                              void* d_out, int out_size, void* d_ws, size_t ws_size,
                              hipStream_t stream) {
  const float* x        = (const float*)d_in[0];
  const float* w_qkv    = (const float*)d_in[1];
  const float* bn_qkv_g = (const float*)d_in[2];
  const float* bn_qkv_b = (const float*)d_in[3];
  const float* bn_sim_g = (const float*)d_in[4];
  const float* bn_sim_b = (const float*)d_in[5];
  const float* bn_out_g = (const float*)d_in[6];
  const float* bn_out_b = (const float*)d_in[7];
  const float* in_w     = (const float*)d_in[8];
  const float* in_b     = (const float*)d_in[9];
  const float* mlp_w1   = (const float*)d_in[10];
  const float* mlp_w2   = (const float*)d_in[11];
  const float* base_rel = (const float*)d_in[12];
  float* Wp = (float*)d_ws;

  __half* relA2  = (__half*)(Wp + 0);        // 17,680 f
  __half* relAT2 = (__half*)(Wp + 17680);    // 17,680 f
  __half* veA    = (__half*)(Wp + 35360);    // 67,584 f
  float* yT      = Wp + 102944;              // 4,194,304
  float* yStd    = Wp + 4297248;             // 4,194,304
  short* wqb     = (short*)(Wp + 8491552);   // 32,768 shorts
  short* w1b     = (short*)(Wp + 8507936);   // 65,536 shorts
  short* w2b     = (short*)(Wp + 8540704);   // 65,536 shorts
  short* xnb     = (short*)(Wp + 8573472);   // 4,194,304 shorts
  short* qkva    = (short*)(Wp + 10670624);  // 4,259,840 shorts (dead after attn)
  short* h1b     = (short*)(Wp + 10670624);  // 16,777,216 shorts (overlays qkva)
  // peak: 19,059,232 floats = 76.2 MB

  k_prep<<<dim3(1049), dim3(256), 0, stream>>>(base_rel, w_qkv, mlp_w1, mlp_w2,
                                               wqb, w1b, w2b, relA2, relAT2, veA);
  k_qkv_mfma<<<dim3(2, 65, 2), dim3(256), 0, stream>>>(x, wqb, bn_qkv_g, bn_qkv_b, qkva);
  k_attn<<<dim3(2048), dim3(256), 0, stream>>>(qkva, relA2, relAT2, veA,
                                               bn_sim_g, bn_sim_b, bn_out_g, bn_out_b, yT);
  k_xs<<<dim3(316), dim3(256), 0, stream>>>(yT, in_w, in_b, xnb, yStd);
  k_mlp1_mfma<<<dim3(4, 128, 2), dim3(256), 0, stream>>>(xnb, w1b, h1b);
  k_mlp2_mfma<<<dim3(128, 1, 2), dim3(256), 0, stream>>>(h1b, w2b, yStd, (float*)d_out);
}

// Round 15
// 145.894 us; speedup vs baseline: 1.7066x; 1.1055x over previous
//
#include <hip/hip_runtime.h>
#include <hip/hip_bf16.h>
#include <hip/hip_fp16.h>

#define GG 8
#define AA 65
#define BB 256

typedef __attribute__((ext_vector_type(8))) short bf16x8;
typedef __attribute__((ext_vector_type(4))) short s16x4;
typedef __attribute__((ext_vector_type(4))) float f32x4;
typedef _Float16 hf2 __attribute__((ext_vector_type(2)));
#define MFMA16(a, b, c) __builtin_amdgcn_mfma_f32_16x16x32_bf16(a, b, c, 0, 0, 0)
#define FDOT2(a, b, c) __builtin_amdgcn_fdot2((a), (b), (c), false)

__device__ __forceinline__ void rz_taps(int o, float scale, int in_size,
                                        int& ia, int& ib, float& f) {
  float pos = (o + 0.5f) * scale - 0.5f;
  float fl = floorf(pos);
  int i0 = (int)fl;
  f = pos - fl;
  ia = i0 < 0 ? 0 : i0;
  int i1 = i0 + 1;
  ib = i1 > (in_size - 1) ? (in_size - 1) : i1;
}

// Compile-time 128->65 tap: pos = (j+0.5)*65/128-0.5 = (130j-63)/256 exactly.
#define JTAP(jc, ja, jb, fj) \
  const int num_ = 130 * (jc) - 63;               \
  const int fl_ = num_ >> 8;                      \
  const int ja = fl_ < 0 ? 0 : fl_;               \
  const int jb = (fl_ + 1 > 64) ? 64 : (fl_ + 1); \
  const float fj = (float)(num_ - (fl_ << 8)) * 0.00390625f;

__device__ __forceinline__ float gelu_exact(float v) {
  return 0.5f * v * (1.0f + erff(v * 0.70710678118654752f));
}

__device__ __forceinline__ short f2b(float f) {
  __hip_bfloat16 h = __float2bfloat16(f);
  return *reinterpret_cast<short*>(&h);
}
__device__ __forceinline__ float b2f(short s) {
  unsigned int u = ((unsigned int)(unsigned short)s) << 16;
  return __uint_as_float(u);
}

#define RSBN 0.99999500003749977f  // 1/sqrt(1+1e-5)

// ---------- PREP: weights->bf16, relA2/relAT2 (fp16 c-pair packed), veA ----------
__global__ void k_prep(const float* __restrict__ base, const float* __restrict__ wq,
                       const float* __restrict__ w1, const float* __restrict__ w2,
                       short* __restrict__ wqb, short* __restrict__ w1b,
                       short* __restrict__ w2b, __half* __restrict__ relA2h,
                       __half* __restrict__ relAT2h, __half* __restrict__ veA) {
  int blk = blockIdx.x;
  int tt = threadIdx.x;
  if (blk < 256) {             // weights
    int i = blk * 256 + tt;
    if (i < 32768) wqb[i] = f2b(wq[i]);
    w1b[i] = f2b(w1[i]);
    w2b[i] = f2b(w2[i]);
    return;
  }
  blk -= 256;
  if (blk < 265) {             // q_emb / k_emb^T, fp16 c-pair dword layout [cp][i][68]
    int idx = blk * 256 + tt;
    if (idx >= 16 * AA * AA) return;
    int j = idx % AA;
    int r = idx / AA;
    int i = r % AA;
    int c = r / AA;
    int ia, ib, ja, jb; float fi, fj;
    rz_taps(i, 255.0f / 65.0f, 255, ia, ib, fi);
    rz_taps(j, 255.0f / 65.0f, 255, ja, jb, fj);
    const float* S = base + (size_t)c * 255 * 255;
    float v = (1.0f - fi) * ((1.0f - fj) * S[ia * 255 + ja] + fj * S[ia * 255 + jb])
            + fi * ((1.0f - fj) * S[ib * 255 + ja] + fj * S[ib * 255 + jb]);
    if (c < 8) {
      relA2h[((((c >> 1) * 4420) + i * 68 + j) << 1) + (c & 1)] = __float2half(v);
    } else {
      int c2 = c - 8;
      relAT2h[((((c2 >> 1) * 4420) + j * 68 + i) << 1) + (c2 & 1)] = __float2half(v);
    }
    return;
  }
  blk -= 265;
  {  // veA[c][ap][128i] half2 (wave-coalesced: i innermost): i-upsampled v_emb
    int idx = blk * 256 + tt;  // 16*66*128 = 135,168
    if (idx >= 16 * 66 * 128) return;
    int i = idx & 127;
    int r = idx >> 7;
    int a = r % 66, c = r / 66;
    float v = 0.f;
    if (a < 65) {
      int ia, ib; float fi;
      rz_taps(i, 65.0f / 128.0f, 65, ia, ib, fi);
      int ja, jb; float fj;
      rz_taps(a, 255.0f / 65.0f, 255, ja, jb, fj);
      int p0a, p0b; float g0;
      rz_taps(ia, 255.0f / 65.0f, 255, p0a, p0b, g0);
      int p1a, p1b; float g1;
      rz_taps(ib, 255.0f / 65.0f, 255, p1a, p1b, g1);
      const float* S = base + (size_t)(16 + c) * 255 * 255;
      float r0 = (1.0f - g0) * ((1.0f - fj) * S[p0a * 255 + ja] + fj * S[p0a * 255 + jb])
               + g0 * ((1.0f - fj) * S[p0b * 255 + ja] + fj * S[p0b * 255 + jb]);
      float r1 = (1.0f - g1) * ((1.0f - fj) * S[p1a * 255 + ja] + fj * S[p1a * 255 + jb])
               + g1 * ((1.0f - fj) * S[p1b * 255 + ja] + fj * S[p1b * 255 + jb]);
      v = (1.0f - fi) * r0 + fi * r1;
    }
    veA[((size_t)(c * 33 + (a >> 1)) * 128 + i) * 2 + (a & 1)] = __float2half(v);
  }
}

// ---------- MFMA GEMM 1: qkva[n][o][a][w] = bf16(BN(Wqkv . downsample_i(x))) ----------
// p-split: 64-wide w tiles -> 520 blocks (2/CU). Fused i-downsample in B staging.
__global__ __launch_bounds__(256) void k_qkv_mfma(
    const float* __restrict__ x, const short* __restrict__ wqb,
    const float* __restrict__ bg, const float* __restrict__ bb,
    short* __restrict__ out) {
  const int ob = blockIdx.x * 128;
  const int ya = blockIdx.y;           // a*2 + p-half
  const int a = ya >> 1;
  const int pb = (ya & 1) * 64;
  const int n = blockIdx.z;
  __shared__ short Asm[128 * 40];
  __shared__ short Bsm[64 * 40];
  const int t = threadIdx.x;
  const int lane = t & 63, wv = t >> 6;
  const int wm = wv >> 1, wn = wv & 1;
  const int lr = lane & 15, lk = (lane >> 4) * 8;
  int ia, ib; float f;
  rz_taps(a, 128.0f / 65.0f, 128, ia, ib, f);
  const float f0 = 1.0f - f;
  f32x4 acc[4][2];
  #pragma unroll
  for (int i = 0; i < 4; ++i)
    #pragma unroll
    for (int j = 0; j < 2; ++j)
      #pragma unroll
      for (int q = 0; q < 4; ++q) acc[i][j][q] = 0.f;
  const float* X = x + (size_t)n * 128 * 16384;
  for (int k0 = 0; k0 < 128; k0 += 32) {
    #pragma unroll
    for (int i2 = 0; i2 < 2; ++i2) {
      int u = t + 256 * i2;
      int row = u >> 2, kq = (u & 3) * 8;
      *(bf16x8*)&Asm[row * 40 + kq] = *(const bf16x8*)&wqb[(ob + row) * 128 + k0 + kq];
    }
    {
      int k = t >> 3, p8 = (t & 7) * 8;
      int c = k0 + k;
      const float* rowA = X + ((size_t)c * 128 + ia) * 128 + pb + p8;
      const float* rowB = X + ((size_t)c * 128 + ib) * 128 + pb + p8;
      float4 a0 = *(const float4*)rowA;
      float4 a1 = *(const float4*)(rowA + 4);
      float4 b0 = *(const float4*)rowB;
      float4 b1 = *(const float4*)(rowB + 4);
      short* d = &Bsm[p8 * 40 + k];
      d[0 * 40] = f2b(f0 * a0.x + f * b0.x);
      d[1 * 40] = f2b(f0 * a0.y + f * b0.y);
      d[2 * 40] = f2b(f0 * a0.z + f * b0.z);
      d[3 * 40] = f2b(f0 * a0.w + f * b0.w);
      d[4 * 40] = f2b(f0 * a1.x + f * b1.x);
      d[5 * 40] = f2b(f0 * a1.y + f * b1.y);
      d[6 * 40] = f2b(f0 * a1.z + f * b1.z);
      d[7 * 40] = f2b(f0 * a1.w + f * b1.w);
    }
    __syncthreads();
    bf16x8 af[4], bfr[2];
    #pragma unroll
    for (int mf = 0; mf < 4; ++mf) af[mf] = *(bf16x8*)&Asm[(wm * 64 + mf * 16 + lr) * 40 + lk];
    #pragma unroll
    for (int nf = 0; nf < 2; ++nf) bfr[nf] = *(bf16x8*)&Bsm[(wn * 32 + nf * 16 + lr) * 40 + lk];
    #pragma unroll
    for (int mf = 0; mf < 4; ++mf)
      #pragma unroll
      for (int nf = 0; nf < 2; ++nf)
        acc[mf][nf] = MFMA16(af[mf], bfr[nf], acc[mf][nf]);
    __syncthreads();
  }
  #pragma unroll
  for (int mf = 0; mf < 4; ++mf) {
    #pragma unroll
    for (int r = 0; r < 4; ++r) {
      int o = ob + wm * 64 + mf * 16 + (lane >> 4) * 4 + r;
      float sc = bg[o] * RSBN, sh = bb[o];
      #pragma unroll
      for (int nf = 0; nf < 2; ++nf) {
        int p = pb + wn * 32 + nf * 16 + lr;
        out[((size_t)(n * 256 + o) * 65 + a) * 128 + p] = f2b(acc[mf][nf][r] * sc + sh);
      }
    }
  }
}

// ---------- F: fused sim(fp16 dot2) + softmax + dot2 sv/sve + bn_out ----------
__global__ void k_attn(const short* __restrict__ qkva, const __half* __restrict__ relA2,
                       const __half* __restrict__ relAT2, const __half* __restrict__ veA,
                       const float* __restrict__ sg, const float* __restrict__ sb,
                       const float* __restrict__ og, const float* __restrict__ ob,
                       float* __restrict__ yT) {
  int orig = blockIdx.x;
  int bg = ((orig & 7) << 8) + (orig >> 3);  // bijective XCD-chunk swizzle
  int b = bg >> 3, g = bg & 7;
  int n = b >> 7, w = b & 127;
  __shared__ float Ss[65 * 68];          // 17,680 B; reused as PwsH after sync
  __shared__ float u0[536];              // 2,144 B: qs2(260dw)+ks2(272dw); vasH after
  __shared__ float Pinvs[128];           // 512 B -> 20,336 B total
  __half* PwsH = (__half*)Ss;
  hf2* qs2 = (hf2*)u0;
  hf2* ks2v = (hf2*)(u0 + 260);
  float* ks2f = u0 + 260;
  __half* vasH = (__half*)u0;
  int t = threadIdx.x;
  const short* Qbase = qkva + ((size_t)(n * 256 + g * 32) * 65) * 128 + w;

  // phase 1: stage q,k as fp16 c-pairs (bf16 -> fp16 exact for these magnitudes)
  for (int l = t; l < 520; l += 256) {
    int isQ = (l < 260);
    int u2 = isQ ? l : l - 260;
    int cp = u2 / 65, a = u2 - cp * 65;
    int cbase = (cp << 1) + (isQ ? 0 : 8);
    float v0 = b2f(Qbase[(size_t)(cbase * 65 + a) * 128]);
    float v1 = b2f(Qbase[(size_t)((cbase + 1) * 65 + a) * 128]);
    hf2 h;
    h[0] = (_Float16)v0;
    h[1] = (_Float16)v1;
    if (isQ) qs2[cp * 65 + a] = h;
    else ks2v[cp * 68 + a] = h;
  }
  __syncthreads();

  // phase 2: sim 65x65 via packed fdot2 (qk+qr+kr, BN-combined)
  {
    float sqk = sg[g] * RSBN, sqr = sg[8 + g] * RSBN, skr = sg[16 + g] * RSBN;
    float badd = sb[g] + sb[8 + g] + sb[16 + g];
    const float* rAf = (const float*)relA2;
    const float* rTf = (const float*)relAT2;
    const hf2* rAv = (const hf2*)relA2;
    const hf2* rTv = (const hf2*)relAT2;
    for (int u = t; u < 65 * 17; u += 256) {
      int i = u / 17, jq = u - i * 17;
      hf2 q2[4];
      #pragma unroll
      for (int cp = 0; cp < 4; ++cp) q2[cp] = qs2[cp * 65 + i];
      if (jq < 16) {
        int j0 = jq * 4;
        int lofs = i * 68 + j0;
        float qk0 = 0, qk1 = 0, qk2 = 0, qk3 = 0;
        float qr0 = 0, qr1 = 0, qr2 = 0, qr3 = 0;
        float kr0 = 0, kr1 = 0, kr2 = 0, kr3 = 0;
        #pragma unroll
        for (int cp = 0; cp < 4; ++cp) {
          float4 kq = *(const float4*)&ks2f[cp * 68 + j0];
          float4 ra = *(const float4*)&rAf[cp * 4420 + lofs];
          float4 rt = *(const float4*)&rTf[cp * 4420 + lofs];
          hf2 k0 = __builtin_bit_cast(hf2, kq.x);
          hf2 k1 = __builtin_bit_cast(hf2, kq.y);
          hf2 k2h = __builtin_bit_cast(hf2, kq.z);
          hf2 k3 = __builtin_bit_cast(hf2, kq.w);
          qk0 = FDOT2(k0, q2[cp], qk0);
          qk1 = FDOT2(k1, q2[cp], qk1);
          qk2 = FDOT2(k2h, q2[cp], qk2);
          qk3 = FDOT2(k3, q2[cp], qk3);
          qr0 = FDOT2(__builtin_bit_cast(hf2, ra.x), q2[cp], qr0);
          qr1 = FDOT2(__builtin_bit_cast(hf2, ra.y), q2[cp], qr1);
          qr2 = FDOT2(__builtin_bit_cast(hf2, ra.z), q2[cp], qr2);
          qr3 = FDOT2(__builtin_bit_cast(hf2, ra.w), q2[cp], qr3);
          kr0 = FDOT2(__builtin_bit_cast(hf2, rt.x), k0, kr0);
          kr1 = FDOT2(__builtin_bit_cast(hf2, rt.y), k1, kr1);
          kr2 = FDOT2(__builtin_bit_cast(hf2, rt.z), k2h, kr2);
          kr3 = FDOT2(__builtin_bit_cast(hf2, rt.w), k3, kr3);
        }
        float4 res;
        res.x = sqk * qk0 + sqr * qr0 + skr * kr0 + badd;
        res.y = sqk * qk1 + sqr * qr1 + skr * kr1 + badd;
        res.z = sqk * qk2 + sqr * qr2 + skr * kr2 + badd;
        res.w = sqk * qk3 + sqr * qr3 + skr * kr3 + badd;
        *(float4*)&Ss[lofs] = res;
      } else {
        int lofs = i * 68 + 64;
        float qk = 0, qr = 0, kr = 0;
        #pragma unroll
        for (int cp = 0; cp < 4; ++cp) {
          hf2 kv = ks2v[cp * 68 + 64];
          qk = FDOT2(kv, q2[cp], qk);
          qr = FDOT2(rAv[cp * 4420 + lofs], q2[cp], qr);
          kr = FDOT2(rTv[cp * 4420 + lofs], kv, kr);
        }
        Ss[lofs] = sqk * qk + sqr * qr + skr * kr + badd;
      }
    }
  }
  __syncthreads();

  // phase 3: v stage (overlays u0) + register-T softmax fold
  for (int l = t; l < 16 * 66; l += 256) {
    int c = l / 66, a = l - c * 66;
    float v = (a < 65) ? b2f(Qbase[(size_t)((16 + c) * 65 + a) * 128]) : 0.f;
    vasH[l] = __float2half(v);
  }
  {
    const int i = t >> 1, h = t & 1;
    int ia, ib; float fi;
    rz_taps(i, 65.0f / 128.0f, 65, ia, ib, fi);
    const float* r0 = Ss + ia * 68 + h * 32;
    const float* r1 = Ss + ib * 68 + h * 32;
    const float wi0 = 1.0f - fi;
    float T[33];
    #pragma unroll
    for (int k4 = 0; k4 < 8; ++k4) {
      float4 a4 = *(const float4*)(r0 + 4 * k4);
      float4 b4 = *(const float4*)(r1 + 4 * k4);
      T[4 * k4 + 0] = wi0 * a4.x + fi * b4.x;
      T[4 * k4 + 1] = wi0 * a4.y + fi * b4.y;
      T[4 * k4 + 2] = wi0 * a4.z + fi * b4.z;
      T[4 * k4 + 3] = wi0 * a4.w + fi * b4.w;
    }
    T[32] = wi0 * r0[32] + fi * r1[32];
    float mx = T[0];
    #pragma unroll
    for (int k = 1; k < 33; ++k) mx = fmaxf(mx, T[k]);
    mx = fmaxf(mx, __shfl_xor(mx, 1));
    float p[33];
    #pragma unroll
    for (int k = 0; k < 33; ++k) p[k] = 0.f;
    float sum = 0.f;
    if (h == 0) {
      #pragma unroll
      for (int j = 0; j < 64; ++j) {
        JTAP(j, ja, jb, fj);
        float v = (1.0f - fj) * T[ja] + fj * T[jb];
        float e = __expf(v - mx);
        sum += e;
        p[ja] += e * (1.0f - fj);
        p[jb] += e * fj;
      }
    } else {
      #pragma unroll
      for (int j = 64; j < 128; ++j) {
        JTAP(j, ja, jb, fj);
        float v = (1.0f - fj) * T[ja - 32] + fj * T[jb - 32];
        float e = __expf(v - mx);
        sum += e;
        p[ja - 32] += e * (1.0f - fj);
        p[jb - 32] += e * fj;
      }
    }
    sum += __shfl_xor(sum, 1);
    float other = __shfl_xor(h ? p[0] : p[32], 1);
    __syncthreads();   // all Ss reads complete before Pw overwrites the same LDS
    __half* prow = &PwsH[i * 66];
    if (h == 0) {
      p[32] += other;
      #pragma unroll
      for (int k = 0; k < 33; ++k) prow[k] = __float2half(p[k]);
      Pinvs[i] = 1.0f / sum;
    } else {
      p[0] += other;
      #pragma unroll
      for (int k = 0; k < 33; ++k) prow[32 + k] = __float2half(p[k]);
      prow[65] = __float2half(0.f);
    }
  }
  __syncthreads();

  // phase 4: dot2 contraction over 33 a-pairs; 2-chain ILP; wave-coalesced veA
  {
    const int i = t & 127;
    const int cg = t >> 7;
    const float inv = Pinvs[i];
    hf2 pw[33];
    const hf2* prow2 = (const hf2*)&PwsH[i * 66];
    #pragma unroll
    for (int ap = 0; ap < 33; ++ap) pw[ap] = prow2[ap];
    #pragma unroll
    for (int l = 0; l < 8; ++l) {
      const int c = cg * 8 + l;
      const hf2* vr = (const hf2*)&vasH[c * 66];
      const hf2* vp = (const hf2*)veA + (size_t)(c * 33) * 128 + i;
      float sv0 = 0.f, sv1 = 0.f, se0 = 0.f, se1 = 0.f;
      #pragma unroll
      for (int ap = 0; ap < 32; ap += 2) {
        sv0 = FDOT2(vr[ap], pw[ap], sv0);
        sv1 = FDOT2(vr[ap + 1], pw[ap + 1], sv1);
        se0 = FDOT2(vp[(size_t)ap * 128], pw[ap], se0);
        se1 = FDOT2(vp[(size_t)(ap + 1) * 128], pw[ap + 1], se1);
      }
      sv0 = FDOT2(vr[32], pw[32], sv0);
      se0 = FDOT2(vp[(size_t)32 * 128], pw[32], se0);
      float sv = sv0 + sv1, se = se0 + se1;
      int c2 = g * 16 + c;
      int o0 = 2 * c2;
      float val = og[o0] * RSBN * (sv * inv) + ob[o0]
                + og[o0 + 1] * RSBN * (se * inv) + ob[o0 + 1];
      yT[((size_t)(n * 128 + c2)) * 16384 + w * 128 + i] = val;
    }
  }
}

// ---------- XS: stage yT plane (fp32 LDS), emit xnb (shift+IN, bf16) + yStd (fp32) ----------
__global__ __launch_bounds__(256) void k_xs(const float* __restrict__ yT,
                                            const float* __restrict__ inw,
                                            const float* __restrict__ inb,
                                            short* __restrict__ xnb,
                                            float* __restrict__ yStd) {
  int gid = blockIdx.x;
  int n, cs, cx = -1;
  bool wStd;
  if (gid < 256) {
    n = gid >> 7; cx = gid & 127;
    cs = (cx < 40) ? (cx % 10) : cx;
    wStd = (cx < 10) || (cx >= 40);
  } else {
    int u = gid - 256;
    n = u / 30; cs = 10 + (u % 30);
    wStd = true;
  }
  int dh = 0, dw = 0;
  if (cx >= 0) {
    if (cx < 10)       dw = -2;
    else if (cx < 20)  dw = 2;
    else if (cx < 30)  dh = -2;
    else if (cx < 40)  dh = 2;
  }
  __shared__ float Sb[128 * 130];
  __shared__ float sm[8];
  const float* src = yT + ((size_t)(n * 128 + cs)) * 16384;
  int t = threadIdx.x;
  #pragma unroll
  for (int l = 0; l < 16; ++l) {
    int q = t + l * 256;
    float4 v = *(const float4*)&src[q * 4];
    int w = q >> 5, i0 = (q * 4) & 127;
    float* d = &Sb[w * 130 + i0];
    *(float2*)d = make_float2(v.x, v.y);
    *(float2*)(d + 2) = make_float2(v.z, v.w);
  }
  __syncthreads();
  if (wStd) {
    float* dst = yStd + ((size_t)(n * 128 + cs)) * 16384;
    for (int l = 0; l < 64; ++l) {
      int idx = t + l * 256;
      int h = idx >> 7, w = idx & 127;
      dst[idx] = Sb[w * 130 + h];
    }
  }
  if (cx >= 0) {
    float s = 0.f, q2 = 0.f;
    for (int l = 0; l < 64; ++l) {
      int idx = t + l * 256;
      int h = idx >> 7, w = idx & 127;
      int hs = h + dh, ws = w + dw;
      float v = (hs >= 0 && hs < 128 && ws >= 0 && ws < 128) ? Sb[ws * 130 + hs] : 0.f;
      s += v; q2 += v * v;
    }
    #pragma unroll
    for (int o = 32; o; o >>= 1) { s += __shfl_down(s, o); q2 += __shfl_down(q2, o); }
    if ((t & 63) == 0) { sm[(t >> 6) * 2] = s; sm[(t >> 6) * 2 + 1] = q2; }
    __syncthreads();
    float S_ = sm[0] + sm[2] + sm[4] + sm[6];
    float Q_ = sm[1] + sm[3] + sm[5] + sm[7];
    float mean = S_ * (1.0f / 16384.0f);
    float var = Q_ * (1.0f / 16384.0f) - mean * mean;
    float scale = inw[cx] * rsqrtf(var + 1e-5f);
    float shift = inb[cx] - mean * scale;
    short* dst = xnb + ((size_t)(n * 128 + cx)) * 16384;
    for (int l = 0; l < 64; ++l) {
      int idx = t + l * 256;
      int h = idx >> 7, w = idx & 127;
      int hs = h + dh, ws = w + dw;
      float v = (hs >= 0 && hs < 128 && ws >= 0 && ws < 128) ? Sb[ws * 130 + hs] : 0.f;
      dst[idx] = f2b(v * scale + shift);
    }
  }
}

// ---------- MFMA GEMM 2: h1 = gelu(W1 . xn) ----------
__global__ __launch_bounds__(256) void k_mlp1_mfma(
    const short* __restrict__ xnb, const short* __restrict__ w1b,
    short* __restrict__ h1) {
  const int ob = blockIdx.x * 128;
  const int pb = blockIdx.y * 128;
  const int n = blockIdx.z;
  __shared__ short Asm[128 * 40];
  __shared__ short Bsm[128 * 40];
  const int t = threadIdx.x;
  const int lane = t & 63, wv = t >> 6;
  const int wm = wv >> 1, wn = wv & 1;
  const int lr = lane & 15, lk = (lane >> 4) * 8;
  f32x4 acc[4][4];
  #pragma unroll
  for (int i = 0; i < 4; ++i)
    #pragma unroll
    for (int j = 0; j < 4; ++j)
      #pragma unroll
      for (int q = 0; q < 4; ++q) acc[i][j][q] = 0.f;
  const short* X = xnb + (size_t)n * 128 * 16384;
  for (int k0 = 0; k0 < 128; k0 += 32) {
    #pragma unroll
    for (int i2 = 0; i2 < 2; ++i2) {
      int u = t + 256 * i2;
      int row = u >> 2, kq = (u & 3) * 8;
      *(bf16x8*)&Asm[row * 40 + kq] = *(const bf16x8*)&w1b[(ob + row) * 128 + k0 + kq];
    }
    #pragma unroll
    for (int i2 = 0; i2 < 2; ++i2) {
      int u = t + 256 * i2;
      int k = u >> 4, p8 = (u & 15) * 8;
      bf16x8 hv = *(const bf16x8*)&X[(size_t)(k0 + k) * 16384 + pb + p8];
      #pragma unroll
      for (int j = 0; j < 8; ++j) Bsm[(p8 + j) * 40 + k] = hv[j];
    }
    __syncthreads();
    bf16x8 af[4], bfr[4];
    #pragma unroll
    for (int mf = 0; mf < 4; ++mf) af[mf] = *(bf16x8*)&Asm[(wm * 64 + mf * 16 + lr) * 40 + lk];
    #pragma unroll
    for (int nf = 0; nf < 4; ++nf) bfr[nf] = *(bf16x8*)&Bsm[(wn * 64 + nf * 16 + lr) * 40 + lk];
    #pragma unroll
    for (int mf = 0; mf < 4; ++mf)
      #pragma unroll
      for (int nf = 0; nf < 4; ++nf)
        acc[mf][nf] = MFMA16(af[mf], bfr[nf], acc[mf][nf]);
    __syncthreads();
  }
  #pragma unroll
  for (int mf = 0; mf < 4; ++mf)
    #pragma unroll
    for (int r = 0; r < 4; ++r) {
      int o = ob + wm * 64 + mf * 16 + (lane >> 4) * 4 + r;
      #pragma unroll
      for (int nf = 0; nf < 4; ++nf) {
        int p = pb + wn * 64 + nf * 16 + lr;
        h1[((size_t)(n * 512 + o)) * 16384 + p] = f2b(gelu_exact(acc[mf][nf][r]));
      }
    }
}

// ---------- MFMA GEMM 3: out = W2 . h1 + identity(yStd); p-split 64 -> 512 blocks ----------
__global__ __launch_bounds__(256) void k_mlp2_mfma(
    const short* __restrict__ h1, const short* __restrict__ w2b,
    const float* __restrict__ y, float* __restrict__ out) {
  const int pb = blockIdx.x * 64;
  const int n = blockIdx.z;
  __shared__ short Asm[128 * 40];
  __shared__ short Bsm[64 * 40];
  const int t = threadIdx.x;
  const int lane = t & 63, wv = t >> 6;
  const int wm = wv >> 1, wn = wv & 1;
  const int lr = lane & 15, lk = (lane >> 4) * 8;
  f32x4 acc[4][2];
  #pragma unroll
  for (int i = 0; i < 4; ++i)
    #pragma unroll
    for (int j = 0; j < 2; ++j)
      #pragma unroll
      for (int q = 0; q < 4; ++q) acc[i][j][q] = 0.f;
  const short* H = h1 + (size_t)n * 512 * 16384;
  for (int k0 = 0; k0 < 512; k0 += 32) {
    #pragma unroll
    for (int i2 = 0; i2 < 2; ++i2) {
      int u = t + 256 * i2;
      int row = u >> 2, kq = (u & 3) * 8;
      *(bf16x8*)&Asm[row * 40 + kq] = *(const bf16x8*)&w2b[row * 512 + k0 + kq];
    }
    {
      int k = t >> 3, p8 = (t & 7) * 8;
      bf16x8 hv = *(const bf16x8*)&H[(size_t)(k0 + k) * 16384 + pb + p8];
      #pragma unroll
      for (int j = 0; j < 8; ++j) Bsm[(p8 + j) * 40 + k] = hv[j];
    }
    __syncthreads();
    bf16x8 af[4], bfr[2];
    #pragma unroll
    for (int mf = 0; mf < 4; ++mf) af[mf] = *(bf16x8*)&Asm[(wm * 64 + mf * 16 + lr) * 40 + lk];
    #pragma unroll
    for (int nf = 0; nf < 2; ++nf) bfr[nf] = *(bf16x8*)&Bsm[(wn * 32 + nf * 16 + lr) * 40 + lk];
    #pragma unroll
    for (int mf = 0; mf < 4; ++mf)
      #pragma unroll
      for (int nf = 0; nf < 2; ++nf)
        acc[mf][nf] = MFMA16(af[mf], bfr[nf], acc[mf][nf]);
    __syncthreads();
  }
  #pragma unroll
  for (int mf = 0; mf < 4; ++mf)
    #pragma unroll
    for (int r = 0; r < 4; ++r) {
      int o = wm * 64 + mf * 16 + (lane >> 4) * 4 + r;
      #pragma unroll
      for (int nf = 0; nf < 2; ++nf) {
        int p = pb + wn * 32 + nf * 16 + lr;
        size_t base = ((size_t)(n * 128 + o)) * 16384 + p;
        out[base] = acc[mf][nf][r] + y[base];
      }
    }
}

extern "C" void kernel_launch(void* const* d_in, const int* in_sizes, int n_in,
                              void* d_out, int out_size, void* d_ws, size_t ws_size,
                              hipStream_t stream) {
  const float* x        = (const float*)d_in[0];
  const float* w_qkv    = (const float*)d_in[1];
  const float* bn_qkv_g = (const float*)d_in[2];
  const float* bn_qkv_b = (const float*)d_in[3];
  const float* bn_sim_g = (const float*)d_in[4];
  const float* bn_sim_b = (const float*)d_in[5];
  const float* bn_out_g = (const float*)d_in[6];
  const float* bn_out_b = (const float*)d_in[7];
  const float* in_w     = (const float*)d_in[8];
  const float* in_b     = (const float*)d_in[9];
  const float* mlp_w1   = (const float*)d_in[10];
  const float* mlp_w2   = (const float*)d_in[11];
  const float* base_rel = (const float*)d_in[12];
  float* Wp = (float*)d_ws;

  __half* relA2  = (__half*)(Wp + 0);        // 17,680 f
  __half* relAT2 = (__half*)(Wp + 17680);    // 17,680 f
  __half* veA    = (__half*)(Wp + 35360);    // 67,584 f
  float* yT      = Wp + 102944;              // 4,194,304
  float* yStd    = Wp + 4297248;             // 4,194,304
  short* wqb     = (short*)(Wp + 8491552);   // 32,768 shorts
  short* w1b     = (short*)(Wp + 8507936);   // 65,536 shorts
  short* w2b     = (short*)(Wp + 8540704);   // 65,536 shorts
  short* xnb     = (short*)(Wp + 8573472);   // 4,194,304 shorts
  short* qkva    = (short*)(Wp + 10670624);  // 4,259,840 shorts (dead after attn)
  short* h1b     = (short*)(Wp + 10670624);  // 16,777,216 shorts (overlays qkva)
  // peak: 19,059,232 floats = 76.2 MB

  k_prep<<<dim3(1049), dim3(256), 0, stream>>>(base_rel, w_qkv, mlp_w1, mlp_w2,
                                               wqb, w1b, w2b, relA2, relAT2, veA);
  k_qkv_mfma<<<dim3(2, 130, 2), dim3(256), 0, stream>>>(x, wqb, bn_qkv_g, bn_qkv_b, qkva);
  k_attn<<<dim3(2048), dim3(256), 0, stream>>>(qkva, relA2, relAT2, veA,
                                               bn_sim_g, bn_sim_b, bn_out_g, bn_out_b, yT);
  k_xs<<<dim3(316), dim3(256), 0, stream>>>(yT, in_w, in_b, xnb, yStd);
  k_mlp1_mfma<<<dim3(4, 128, 2), dim3(256), 0, stream>>>(xnb, w1b, h1b);
  k_mlp2_mfma<<<dim3(256, 1, 2), dim3(256), 0, stream>>>(h1b, w2b, yStd, (float*)d_out);
}

// Round 16
// 144.405 us; speedup vs baseline: 1.7242x; 1.0103x over previous
//
#include <hip/hip_runtime.h>
#include <hip/hip_bf16.h>
#include <hip/hip_fp16.h>

#define GG 8
#define AA 65
#define BB 256

typedef __attribute__((ext_vector_type(8))) short bf16x8;
typedef __attribute__((ext_vector_type(4))) short s16x4;
typedef __attribute__((ext_vector_type(4))) float f32x4;
typedef _Float16 hf2 __attribute__((ext_vector_type(2)));
#define MFMA16(a, b, c) __builtin_amdgcn_mfma_f32_16x16x32_bf16(a, b, c, 0, 0, 0)
#define FDOT2(a, b, c) __builtin_amdgcn_fdot2((a), (b), (c), false)

__device__ __forceinline__ void rz_taps(int o, float scale, int in_size,
                                        int& ia, int& ib, float& f) {
  float pos = (o + 0.5f) * scale - 0.5f;
  float fl = floorf(pos);
  int i0 = (int)fl;
  f = pos - fl;
  ia = i0 < 0 ? 0 : i0;
  int i1 = i0 + 1;
  ib = i1 > (in_size - 1) ? (in_size - 1) : i1;
}

// Compile-time 128->65 tap: pos = (j+0.5)*65/128-0.5 = (130j-63)/256 exactly.
#define JTAP(jc, ja, jb, fj) \
  const int num_ = 130 * (jc) - 63;               \
  const int fl_ = num_ >> 8;                      \
  const int ja = fl_ < 0 ? 0 : fl_;               \
  const int jb = (fl_ + 1 > 64) ? 64 : (fl_ + 1); \
  const float fj = (float)(num_ - (fl_ << 8)) * 0.00390625f;

__device__ __forceinline__ float gelu_exact(float v) {
  return 0.5f * v * (1.0f + erff(v * 0.70710678118654752f));
}

__device__ __forceinline__ short f2b(float f) {
  __hip_bfloat16 h = __float2bfloat16(f);
  return *reinterpret_cast<short*>(&h);
}
__device__ __forceinline__ float b2f(short s) {
  unsigned int u = ((unsigned int)(unsigned short)s) << 16;
  return __uint_as_float(u);
}

#define RSBN 0.99999500003749977f  // 1/sqrt(1+1e-5)

// ---------- PREP: weights->bf16, relA2/relAT2 (fp16 c-pair packed), veA4 ----------
__global__ void k_prep(const float* __restrict__ base, const float* __restrict__ wq,
                       const float* __restrict__ w1, const float* __restrict__ w2,
                       short* __restrict__ wqb, short* __restrict__ w1b,
                       short* __restrict__ w2b, __half* __restrict__ relA2h,
                       __half* __restrict__ relAT2h, __half* __restrict__ veA4) {
  int blk = blockIdx.x;
  int tt = threadIdx.x;
  if (blk < 256) {             // weights
    int i = blk * 256 + tt;
    if (i < 32768) wqb[i] = f2b(wq[i]);
    w1b[i] = f2b(w1[i]);
    w2b[i] = f2b(w2[i]);
    return;
  }
  blk -= 256;
  if (blk < 265) {             // q_emb / k_emb^T, fp16 c-pair dword layout [cp][i][68]
    int idx = blk * 256 + tt;
    if (idx >= 16 * AA * AA) return;
    int j = idx % AA;
    int r = idx / AA;
    int i = r % AA;
    int c = r / AA;
    int ia, ib, ja, jb; float fi, fj;
    rz_taps(i, 255.0f / 65.0f, 255, ia, ib, fi);
    rz_taps(j, 255.0f / 65.0f, 255, ja, jb, fj);
    const float* S = base + (size_t)c * 255 * 255;
    float v = (1.0f - fi) * ((1.0f - fj) * S[ia * 255 + ja] + fj * S[ia * 255 + jb])
            + fi * ((1.0f - fj) * S[ib * 255 + ja] + fj * S[ib * 255 + jb]);
    if (c < 8) {
      relA2h[((((c >> 1) * 4420) + i * 68 + j) << 1) + (c & 1)] = __float2half(v);
    } else {
      int c2 = c - 8;
      relAT2h[((((c2 >> 1) * 4420) + j * 68 + i) << 1) + (c2 & 1)] = __float2half(v);
    }
    return;
  }
  blk -= 265;
  {  // veA4[c][ap4][i] float4-groups (8 halves = 8 a's); wave-coalesced AND x4-vector
    int idx = blk * 256 + tt;  // 16*72*128 = 147,456
    if (idx >= 16 * 72 * 128) return;
    int i = idx & 127;
    int r = idx >> 7;
    int a = r % 72, c = r / 72;
    float v = 0.f;
    if (a < 65) {
      int ia, ib; float fi;
      rz_taps(i, 65.0f / 128.0f, 65, ia, ib, fi);
      int ja, jb; float fj;
      rz_taps(a, 255.0f / 65.0f, 255, ja, jb, fj);
      int p0a, p0b; float g0;
      rz_taps(ia, 255.0f / 65.0f, 255, p0a, p0b, g0);
      int p1a, p1b; float g1;
      rz_taps(ib, 255.0f / 65.0f, 255, p1a, p1b, g1);
      const float* S = base + (size_t)(16 + c) * 255 * 255;
      float r0 = (1.0f - g0) * ((1.0f - fj) * S[p0a * 255 + ja] + fj * S[p0a * 255 + jb])
               + g0 * ((1.0f - fj) * S[p0b * 255 + ja] + fj * S[p0b * 255 + jb]);
      float r1 = (1.0f - g1) * ((1.0f - fj) * S[p1a * 255 + ja] + fj * S[p1a * 255 + jb])
               + g1 * ((1.0f - fj) * S[p1b * 255 + ja] + fj * S[p1b * 255 + jb]);
      v = (1.0f - fi) * r0 + fi * r1;
    }
    veA4[(((size_t)(c * 9 + (a >> 3)) * 128 + i) << 3) + (a & 7)] = __float2half(v);
  }
}

// ---------- MFMA GEMM 1: qkva[n][o][a][w] = bf16(BN(Wqkv . downsample_i(x))) ----------
__global__ __launch_bounds__(256) void k_qkv_mfma(
    const float* __restrict__ x, const short* __restrict__ wqb,
    const float* __restrict__ bg, const float* __restrict__ bb,
    short* __restrict__ out) {
  const int ob = blockIdx.x * 128;
  const int ya = blockIdx.y;           // a*2 + p-half
  const int a = ya >> 1;
  const int pb = (ya & 1) * 64;
  const int n = blockIdx.z;
  __shared__ short Asm[128 * 40];
  __shared__ short Bsm[64 * 40];
  const int t = threadIdx.x;
  const int lane = t & 63, wv = t >> 6;
  const int wm = wv >> 1, wn = wv & 1;
  const int lr = lane & 15, lk = (lane >> 4) * 8;
  int ia, ib; float f;
  rz_taps(a, 128.0f / 65.0f, 128, ia, ib, f);
  const float f0 = 1.0f - f;
  f32x4 acc[4][2];
  #pragma unroll
  for (int i = 0; i < 4; ++i)
    #pragma unroll
    for (int j = 0; j < 2; ++j)
      #pragma unroll
      for (int q = 0; q < 4; ++q) acc[i][j][q] = 0.f;
  const float* X = x + (size_t)n * 128 * 16384;
  for (int k0 = 0; k0 < 128; k0 += 32) {
    #pragma unroll
    for (int i2 = 0; i2 < 2; ++i2) {
      int u = t + 256 * i2;
      int row = u >> 2, kq = (u & 3) * 8;
      *(bf16x8*)&Asm[row * 40 + kq] = *(const bf16x8*)&wqb[(ob + row) * 128 + k0 + kq];
    }
    {
      int k = t >> 3, p8 = (t & 7) * 8;
      int c = k0 + k;
      const float* rowA = X + ((size_t)c * 128 + ia) * 128 + pb + p8;
      const float* rowB = X + ((size_t)c * 128 + ib) * 128 + pb + p8;
      float4 a0 = *(const float4*)rowA;
      float4 a1 = *(const float4*)(rowA + 4);
      float4 b0 = *(const float4*)rowB;
      float4 b1 = *(const float4*)(rowB + 4);
      short* d = &Bsm[p8 * 40 + k];
      d[0 * 40] = f2b(f0 * a0.x + f * b0.x);
      d[1 * 40] = f2b(f0 * a0.y + f * b0.y);
      d[2 * 40] = f2b(f0 * a0.z + f * b0.z);
      d[3 * 40] = f2b(f0 * a0.w + f * b0.w);
      d[4 * 40] = f2b(f0 * a1.x + f * b1.x);
      d[5 * 40] = f2b(f0 * a1.y + f * b1.y);
      d[6 * 40] = f2b(f0 * a1.z + f * b1.z);
      d[7 * 40] = f2b(f0 * a1.w + f * b1.w);
    }
    __syncthreads();
    bf16x8 af[4], bfr[2];
    #pragma unroll
    for (int mf = 0; mf < 4; ++mf) af[mf] = *(bf16x8*)&Asm[(wm * 64 + mf * 16 + lr) * 40 + lk];
    #pragma unroll
    for (int nf = 0; nf < 2; ++nf) bfr[nf] = *(bf16x8*)&Bsm[(wn * 32 + nf * 16 + lr) * 40 + lk];
    #pragma unroll
    for (int mf = 0; mf < 4; ++mf)
      #pragma unroll
      for (int nf = 0; nf < 2; ++nf)
        acc[mf][nf] = MFMA16(af[mf], bfr[nf], acc[mf][nf]);
    __syncthreads();
  }
  #pragma unroll
  for (int mf = 0; mf < 4; ++mf) {
    #pragma unroll
    for (int r = 0; r < 4; ++r) {
      int o = ob + wm * 64 + mf * 16 + (lane >> 4) * 4 + r;
      float sc = bg[o] * RSBN, sh = bb[o];
      #pragma unroll
      for (int nf = 0; nf < 2; ++nf) {
        int p = pb + wn * 32 + nf * 16 + lr;
        out[((size_t)(n * 256 + o) * 65 + a) * 128 + p] = f2b(acc[mf][nf][r] * sc + sh);
      }
    }
  }
}

// ---------- F: fused sim(fp16 dot2) + softmax + x4-dot2 sv/sve + bn_out ----------
__global__ void k_attn(const short* __restrict__ qkva, const __half* __restrict__ relA2,
                       const __half* __restrict__ relAT2, const __half* __restrict__ veA4,
                       const float* __restrict__ sg, const float* __restrict__ sb,
                       const float* __restrict__ og, const float* __restrict__ ob,
                       float* __restrict__ yT) {
  int orig = blockIdx.x;
  int bg = ((orig & 7) << 8) + (orig >> 3);  // bijective XCD-chunk swizzle
  int b = bg >> 3, g = bg & 7;
  int n = b >> 7, w = b & 127;
  __shared__ __attribute__((aligned(16))) float Ss[65 * 68];  // 17,680 B; PwsH after sync
  __shared__ __attribute__((aligned(16))) float u0[576];      // 2,304 B: qs2+ks2; vasH(16*72h)
  __shared__ float Pinvs[128];                                // 512 B -> 20,496 B total
  __half* PwsH = (__half*)Ss;
  hf2* qs2 = (hf2*)u0;
  hf2* ks2v = (hf2*)(u0 + 260);
  float* ks2f = u0 + 260;
  __half* vasH = (__half*)u0;
  int t = threadIdx.x;
  const short* Qbase = qkva + ((size_t)(n * 256 + g * 32) * 65) * 128 + w;

  // phase 1: stage q,k as fp16 c-pairs (bf16 -> fp16 exact for these magnitudes)
  for (int l = t; l < 520; l += 256) {
    int isQ = (l < 260);
    int u2 = isQ ? l : l - 260;
    int cp = u2 / 65, a = u2 - cp * 65;
    int cbase = (cp << 1) + (isQ ? 0 : 8);
    float v0 = b2f(Qbase[(size_t)(cbase * 65 + a) * 128]);
    float v1 = b2f(Qbase[(size_t)((cbase + 1) * 65 + a) * 128]);
    hf2 h;
    h[0] = (_Float16)v0;
    h[1] = (_Float16)v1;
    if (isQ) qs2[cp * 65 + a] = h;
    else ks2v[cp * 68 + a] = h;
  }
  __syncthreads();

  // phase 2: sim 65x65 via packed fdot2 (qk+qr+kr, BN-combined)
  {
    float sqk = sg[g] * RSBN, sqr = sg[8 + g] * RSBN, skr = sg[16 + g] * RSBN;
    float badd = sb[g] + sb[8 + g] + sb[16 + g];
    const float* rAf = (const float*)relA2;
    const float* rTf = (const float*)relAT2;
    const hf2* rAv = (const hf2*)relA2;
    const hf2* rTv = (const hf2*)relAT2;
    for (int u = t; u < 65 * 17; u += 256) {
      int i = u / 17, jq = u - i * 17;
      hf2 q2[4];
      #pragma unroll
      for (int cp = 0; cp < 4; ++cp) q2[cp] = qs2[cp * 65 + i];
      if (jq < 16) {
        int j0 = jq * 4;
        int lofs = i * 68 + j0;
        float qk0 = 0, qk1 = 0, qk2 = 0, qk3 = 0;
        float qr0 = 0, qr1 = 0, qr2 = 0, qr3 = 0;
        float kr0 = 0, kr1 = 0, kr2 = 0, kr3 = 0;
        #pragma unroll
        for (int cp = 0; cp < 4; ++cp) {
          float4 kq = *(const float4*)&ks2f[cp * 68 + j0];
          float4 ra = *(const float4*)&rAf[cp * 4420 + lofs];
          float4 rt = *(const float4*)&rTf[cp * 4420 + lofs];
          hf2 k0 = __builtin_bit_cast(hf2, kq.x);
          hf2 k1 = __builtin_bit_cast(hf2, kq.y);
          hf2 k2h = __builtin_bit_cast(hf2, kq.z);
          hf2 k3 = __builtin_bit_cast(hf2, kq.w);
          qk0 = FDOT2(k0, q2[cp], qk0);
          qk1 = FDOT2(k1, q2[cp], qk1);
          qk2 = FDOT2(k2h, q2[cp], qk2);
          qk3 = FDOT2(k3, q2[cp], qk3);
          qr0 = FDOT2(__builtin_bit_cast(hf2, ra.x), q2[cp], qr0);
          qr1 = FDOT2(__builtin_bit_cast(hf2, ra.y), q2[cp], qr1);
          qr2 = FDOT2(__builtin_bit_cast(hf2, ra.z), q2[cp], qr2);
          qr3 = FDOT2(__builtin_bit_cast(hf2, ra.w), q2[cp], qr3);
          kr0 = FDOT2(__builtin_bit_cast(hf2, rt.x), k0, kr0);
          kr1 = FDOT2(__builtin_bit_cast(hf2, rt.y), k1, kr1);
          kr2 = FDOT2(__builtin_bit_cast(hf2, rt.z), k2h, kr2);
          kr3 = FDOT2(__builtin_bit_cast(hf2, rt.w), k3, kr3);
        }
        float4 res;
        res.x = sqk * qk0 + sqr * qr0 + skr * kr0 + badd;
        res.y = sqk * qk1 + sqr * qr1 + skr * kr1 + badd;
        res.z = sqk * qk2 + sqr * qr2 + skr * kr2 + badd;
        res.w = sqk * qk3 + sqr * qr3 + skr * kr3 + badd;
        *(float4*)&Ss[lofs] = res;
      } else {
        int lofs = i * 68 + 64;
        float qk = 0, qr = 0, kr = 0;
        #pragma unroll
        for (int cp = 0; cp < 4; ++cp) {
          hf2 kv = ks2v[cp * 68 + 64];
          qk = FDOT2(kv, q2[cp], qk);
          qr = FDOT2(rAv[cp * 4420 + lofs], q2[cp], qr);
          kr = FDOT2(rTv[cp * 4420 + lofs], kv, kr);
        }
        Ss[lofs] = sqk * qk + sqr * qr + skr * kr + badd;
      }
    }
  }
  __syncthreads();

  // phase 3: v stage (fp16, a padded to 72, overlays u0) + register-T softmax fold
  for (int l = t; l < 16 * 72; l += 256) {
    int c = l / 72, a = l - c * 72;
    float v = (a < 65) ? b2f(Qbase[(size_t)((16 + c) * 65 + a) * 128]) : 0.f;
    vasH[l] = __float2half(v);
  }
  {
    const int i = t >> 1, h = t & 1;
    int ia, ib; float fi;
    rz_taps(i, 65.0f / 128.0f, 65, ia, ib, fi);
    const float* r0 = Ss + ia * 68 + h * 32;
    const float* r1 = Ss + ib * 68 + h * 32;
    const float wi0 = 1.0f - fi;
    float T[33];
    #pragma unroll
    for (int k4 = 0; k4 < 8; ++k4) {
      float4 a4 = *(const float4*)(r0 + 4 * k4);
      float4 b4 = *(const float4*)(r1 + 4 * k4);
      T[4 * k4 + 0] = wi0 * a4.x + fi * b4.x;
      T[4 * k4 + 1] = wi0 * a4.y + fi * b4.y;
      T[4 * k4 + 2] = wi0 * a4.z + fi * b4.z;
      T[4 * k4 + 3] = wi0 * a4.w + fi * b4.w;
    }
    T[32] = wi0 * r0[32] + fi * r1[32];
    float mx = T[0];
    #pragma unroll
    for (int k = 1; k < 33; ++k) mx = fmaxf(mx, T[k]);
    mx = fmaxf(mx, __shfl_xor(mx, 1));
    float p[33];
    #pragma unroll
    for (int k = 0; k < 33; ++k) p[k] = 0.f;
    float sum = 0.f;
    if (h == 0) {
      #pragma unroll
      for (int j = 0; j < 64; ++j) {
        JTAP(j, ja, jb, fj);
        float v = (1.0f - fj) * T[ja] + fj * T[jb];
        float e = __expf(v - mx);
        sum += e;
        p[ja] += e * (1.0f - fj);
        p[jb] += e * fj;
      }
    } else {
      #pragma unroll
      for (int j = 64; j < 128; ++j) {
        JTAP(j, ja, jb, fj);
        float v = (1.0f - fj) * T[ja - 32] + fj * T[jb - 32];
        float e = __expf(v - mx);
        sum += e;
        p[ja - 32] += e * (1.0f - fj);
        p[jb - 32] += e * fj;
      }
    }
    sum += __shfl_xor(sum, 1);
    float other = __shfl_xor(h ? p[0] : p[32], 1);
    __syncthreads();   // all Ss reads complete before Pw overwrites the same LDS
    __half* prow = &PwsH[i * 66];
    if (h == 0) {
      p[32] += other;
      #pragma unroll
      for (int k = 0; k < 33; ++k) prow[k] = __float2half(p[k]);
      Pinvs[i] = 1.0f / sum;
    } else {
      p[0] += other;
      #pragma unroll
      for (int k = 0; k < 33; ++k) prow[32 + k] = __float2half(p[k]);
      prow[65] = __float2half(0.f);
    }
  }
  __syncthreads();

  // phase 4: x4-vectorized dot2 (float4 LDS vas + float4 coalesced veA4)
  {
    const int i = t & 127;
    const int cg = t >> 7;
    const float inv = Pinvs[i];
    hf2 pw[33];
    const hf2* prow2 = (const hf2*)&PwsH[i * 66];
    #pragma unroll
    for (int ap = 0; ap < 33; ++ap) pw[ap] = prow2[ap];
    #pragma unroll
    for (int l = 0; l < 8; ++l) {
      const int c = cg * 8 + l;
      const float4* vr4 = (const float4*)&vasH[c * 72];
      const float4* vp4 = (const float4*)veA4 + (size_t)(c * 9) * 128 + i;
      float sv0 = 0.f, sv1 = 0.f, se0 = 0.f, se1 = 0.f;
      #pragma unroll
      for (int q4 = 0; q4 < 8; ++q4) {
        float4 a4 = vr4[q4];
        float4 b4 = vp4[(size_t)q4 * 128];
        sv0 = FDOT2(__builtin_bit_cast(hf2, a4.x), pw[4 * q4 + 0], sv0);
        sv1 = FDOT2(__builtin_bit_cast(hf2, a4.y), pw[4 * q4 + 1], sv1);
        sv0 = FDOT2(__builtin_bit_cast(hf2, a4.z), pw[4 * q4 + 2], sv0);
        sv1 = FDOT2(__builtin_bit_cast(hf2, a4.w), pw[4 * q4 + 3], sv1);
        se0 = FDOT2(__builtin_bit_cast(hf2, b4.x), pw[4 * q4 + 0], se0);
        se1 = FDOT2(__builtin_bit_cast(hf2, b4.y), pw[4 * q4 + 1], se1);
        se0 = FDOT2(__builtin_bit_cast(hf2, b4.z), pw[4 * q4 + 2], se0);
        se1 = FDOT2(__builtin_bit_cast(hf2, b4.w), pw[4 * q4 + 3], se1);
      }
      {  // tail: ap=32 (only .x of the 9th float4 carries data)
        float4 a4 = vr4[8];
        float4 b4 = vp4[(size_t)8 * 128];
        sv0 = FDOT2(__builtin_bit_cast(hf2, a4.x), pw[32], sv0);
        se0 = FDOT2(__builtin_bit_cast(hf2, b4.x), pw[32], se0);
      }
      float sv = sv0 + sv1, se = se0 + se1;
      int c2 = g * 16 + c;
      int o0 = 2 * c2;
      float val = og[o0] * RSBN * (sv * inv) + ob[o0]
                + og[o0 + 1] * RSBN * (se * inv) + ob[o0 + 1];
      yT[((size_t)(n * 128 + c2)) * 16384 + w * 128 + i] = val;
    }
  }
}

// ---------- XS: stage yT plane (fp32 LDS), emit xnb (shift+IN, bf16) + yStd (fp32) ----------
__global__ __launch_bounds__(256) void k_xs(const float* __restrict__ yT,
                                            const float* __restrict__ inw,
                                            const float* __restrict__ inb,
                                            short* __restrict__ xnb,
                                            float* __restrict__ yStd) {
  int gid = blockIdx.x;
  int n, cs, cx = -1;
  bool wStd;
  if (gid < 256) {
    n = gid >> 7; cx = gid & 127;
    cs = (cx < 40) ? (cx % 10) : cx;
    wStd = (cx < 10) || (cx >= 40);
  } else {
    int u = gid - 256;
    n = u / 30; cs = 10 + (u % 30);
    wStd = true;
  }
  int dh = 0, dw = 0;
  if (cx >= 0) {
    if (cx < 10)       dw = -2;
    else if (cx < 20)  dw = 2;
    else if (cx < 30)  dh = -2;
    else if (cx < 40)  dh = 2;
  }
  __shared__ float Sb[128 * 130];
  __shared__ float sm[8];
  const float* src = yT + ((size_t)(n * 128 + cs)) * 16384;
  int t = threadIdx.x;
  #pragma unroll
  for (int l = 0; l < 16; ++l) {
    int q = t + l * 256;
    float4 v = *(const float4*)&src[q * 4];
    int w = q >> 5, i0 = (q * 4) & 127;
    float* d = &Sb[w * 130 + i0];
    *(float2*)d = make_float2(v.x, v.y);
    *(float2*)(d + 2) = make_float2(v.z, v.w);
  }
  __syncthreads();
  if (wStd) {
    float* dst = yStd + ((size_t)(n * 128 + cs)) * 16384;
    for (int l = 0; l < 64; ++l) {
      int idx = t + l * 256;
      int h = idx >> 7, w = idx & 127;
      dst[idx] = Sb[w * 130 + h];
    }
  }
  if (cx >= 0) {
    float s = 0.f, q2 = 0.f;
    for (int l = 0; l < 64; ++l) {
      int idx = t + l * 256;
      int h = idx >> 7, w = idx & 127;
      int hs = h + dh, ws = w + dw;
      float v = (hs >= 0 && hs < 128 && ws >= 0 && ws < 128) ? Sb[ws * 130 + hs] : 0.f;
      s += v; q2 += v * v;
    }
    #pragma unroll
    for (int o = 32; o; o >>= 1) { s += __shfl_down(s, o); q2 += __shfl_down(q2, o); }
    if ((t & 63) == 0) { sm[(t >> 6) * 2] = s; sm[(t >> 6) * 2 + 1] = q2; }
    __syncthreads();
    float S_ = sm[0] + sm[2] + sm[4] + sm[6];
    float Q_ = sm[1] + sm[3] + sm[5] + sm[7];
    float mean = S_ * (1.0f / 16384.0f);
    float var = Q_ * (1.0f / 16384.0f) - mean * mean;
    float scale = inw[cx] * rsqrtf(var + 1e-5f);
    float shift = inb[cx] - mean * scale;
    short* dst = xnb + ((size_t)(n * 128 + cx)) * 16384;
    for (int l = 0; l < 64; ++l) {
      int idx = t + l * 256;
      int h = idx >> 7, w = idx & 127;
      int hs = h + dh, ws = w + dw;
      float v = (hs >= 0 && hs < 128 && ws >= 0 && ws < 128) ? Sb[ws * 130 + hs] : 0.f;
      dst[idx] = f2b(v * scale + shift);
    }
  }
}

// ---------- MFMA GEMM 2: h1 = gelu(W1 . xn) ----------
__global__ __launch_bounds__(256) void k_mlp1_mfma(
    const short* __restrict__ xnb, const short* __restrict__ w1b,
    short* __restrict__ h1) {
  const int ob = blockIdx.x * 128;
  const int pb = blockIdx.y * 128;
  const int n = blockIdx.z;
  __shared__ short Asm[128 * 40];
  __shared__ short Bsm[128 * 40];
  const int t = threadIdx.x;
  const int lane = t & 63, wv = t >> 6;
  const int wm = wv >> 1, wn = wv & 1;
  const int lr = lane & 15, lk = (lane >> 4) * 8;
  f32x4 acc[4][4];
  #pragma unroll
  for (int i = 0; i < 4; ++i)
    #pragma unroll
    for (int j = 0; j < 4; ++j)
      #pragma unroll
      for (int q = 0; q < 4; ++q) acc[i][j][q] = 0.f;
  const short* X = xnb + (size_t)n * 128 * 16384;
  for (int k0 = 0; k0 < 128; k0 += 32) {
    #pragma unroll
    for (int i2 = 0; i2 < 2; ++i2) {
      int u = t + 256 * i2;
      int row = u >> 2, kq = (u & 3) * 8;
      *(bf16x8*)&Asm[row * 40 + kq] = *(const bf16x8*)&w1b[(ob + row) * 128 + k0 + kq];
    }
    #pragma unroll
    for (int i2 = 0; i2 < 2; ++i2) {
      int u = t + 256 * i2;
      int k = u >> 4, p8 = (u & 15) * 8;
      bf16x8 hv = *(const bf16x8*)&X[(size_t)(k0 + k) * 16384 + pb + p8];
      #pragma unroll
      for (int j = 0; j < 8; ++j) Bsm[(p8 + j) * 40 + k] = hv[j];
    }
    __syncthreads();
    bf16x8 af[4], bfr[4];
    #pragma unroll
    for (int mf = 0; mf < 4; ++mf) af[mf] = *(bf16x8*)&Asm[(wm * 64 + mf * 16 + lr) * 40 + lk];
    #pragma unroll
    for (int nf = 0; nf < 4; ++nf) bfr[nf] = *(bf16x8*)&Bsm[(wn * 64 + nf * 16 + lr) * 40 + lk];
    #pragma unroll
    for (int mf = 0; mf < 4; ++mf)
      #pragma unroll
      for (int nf = 0; nf < 4; ++nf)
        acc[mf][nf] = MFMA16(af[mf], bfr[nf], acc[mf][nf]);
    __syncthreads();
  }
  #pragma unroll
  for (int mf = 0; mf < 4; ++mf)
    #pragma unroll
    for (int r = 0; r < 4; ++r) {
      int o = ob + wm * 64 + mf * 16 + (lane >> 4) * 4 + r;
      #pragma unroll
      for (int nf = 0; nf < 4; ++nf) {
        int p = pb + wn * 64 + nf * 16 + lr;
        h1[((size_t)(n * 512 + o)) * 16384 + p] = f2b(gelu_exact(acc[mf][nf][r]));
      }
    }
}

// ---------- MFMA GEMM 3: out = W2 . h1 + identity(yStd); p-split 64 -> 512 blocks ----------
__global__ __launch_bounds__(256) void k_mlp2_mfma(
    const short* __restrict__ h1, const short* __restrict__ w2b,
    const float* __restrict__ y, float* __restrict__ out) {
  const int pb = blockIdx.x * 64;
  const int n = blockIdx.z;
  __shared__ short Asm[128 * 40];
  __shared__ short Bsm[64 * 40];
  const int t = threadIdx.x;
  const int lane = t & 63, wv = t >> 6;
  const int wm = wv >> 1, wn = wv & 1;
  const int lr = lane & 15, lk = (lane >> 4) * 8;
  f32x4 acc[4][2];
  #pragma unroll
  for (int i = 0; i < 4; ++i)
    #pragma unroll
    for (int j = 0; j < 2; ++j)
      #pragma unroll
      for (int q = 0; q < 4; ++q) acc[i][j][q] = 0.f;
  const short* H = h1 + (size_t)n * 512 * 16384;
  for (int k0 = 0; k0 < 512; k0 += 32) {
    #pragma unroll
    for (int i2 = 0; i2 < 2; ++i2) {
      int u = t + 256 * i2;
      int row = u >> 2, kq = (u & 3) * 8;
      *(bf16x8*)&Asm[row * 40 + kq] = *(const bf16x8*)&w2b[row * 512 + k0 + kq];
    }
    {
      int k = t >> 3, p8 = (t & 7) * 8;
      bf16x8 hv = *(const bf16x8*)&H[(size_t)(k0 + k) * 16384 + pb + p8];
      #pragma unroll
      for (int j = 0; j < 8; ++j) Bsm[(p8 + j) * 40 + k] = hv[j];
    }
    __syncthreads();
    bf16x8 af[4], bfr[2];
    #pragma unroll
    for (int mf = 0; mf < 4; ++mf) af[mf] = *(bf16x8*)&Asm[(wm * 64 + mf * 16 + lr) * 40 + lk];
    #pragma unroll
    for (int nf = 0; nf < 2; ++nf) bfr[nf] = *(bf16x8*)&Bsm[(wn * 32 + nf * 16 + lr) * 40 + lk];
    #pragma unroll
    for (int mf = 0; mf < 4; ++mf)
      #pragma unroll
      for (int nf = 0; nf < 2; ++nf)
        acc[mf][nf] = MFMA16(af[mf], bfr[nf], acc[mf][nf]);
    __syncthreads();
  }
  #pragma unroll
  for (int mf = 0; mf < 4; ++mf)
    #pragma unroll
    for (int r = 0; r < 4; ++r) {
      int o = wm * 64 + mf * 16 + (lane >> 4) * 4 + r;
      #pragma unroll
      for (int nf = 0; nf < 2; ++nf) {
        int p = pb + wn * 32 + nf * 16 + lr;
        size_t base = ((size_t)(n * 128 + o)) * 16384 + p;
        out[base] = acc[mf][nf][r] + y[base];
      }
    }
}

extern "C" void kernel_launch(void* const* d_in, const int* in_sizes, int n_in,
                              void* d_out, int out_size, void* d_ws, size_t ws_size,
                              hipStream_t stream) {
  const float* x        = (const float*)d_in[0];
  const float* w_qkv    = (const float*)d_in[1];
  const float* bn_qkv_g = (const float*)d_in[2];
  const float* bn_qkv_b = (const float*)d_in[3];
  const float* bn_sim_g = (const float*)d_in[4];
  const float* bn_sim_b = (const float*)d_in[5];
  const float* bn_out_g = (const float*)d_in[6];
  const float* bn_out_b = (const float*)d_in[7];
  const float* in_w     = (const float*)d_in[8];
  const float* in_b     = (const float*)d_in[9];
  const float* mlp_w1   = (const float*)d_in[10];
  const float* mlp_w2   = (const float*)d_in[11];
  const float* base_rel = (const float*)d_in[12];
  float* Wp = (float*)d_ws;

  __half* relA2  = (__half*)(Wp + 0);        // 17,680 f
  __half* relAT2 = (__half*)(Wp + 17680);    // 17,680 f
  __half* veA4   = (__half*)(Wp + 35360);    // 147,456 halves = 73,728 f
  float* yT      = Wp + 109088;              // 4,194,304
  float* yStd    = Wp + 4303392;             // 4,194,304
  short* wqb     = (short*)(Wp + 8497696);   // 32,768 shorts
  short* w1b     = (short*)(Wp + 8514080);   // 65,536 shorts
  short* w2b     = (short*)(Wp + 8546848);   // 65,536 shorts
  short* xnb     = (short*)(Wp + 8579616);   // 4,194,304 shorts
  short* qkva    = (short*)(Wp + 10676768);  // 4,259,840 shorts (dead after attn)
  short* h1b     = (short*)(Wp + 10676768);  // 16,777,216 shorts (overlays qkva)
  // peak: 19,065,376 floats = 76.3 MB

  k_prep<<<dim3(1097), dim3(256), 0, stream>>>(base_rel, w_qkv, mlp_w1, mlp_w2,
                                               wqb, w1b, w2b, relA2, relAT2, veA4);
  k_qkv_mfma<<<dim3(2, 130, 2), dim3(256), 0, stream>>>(x, wqb, bn_qkv_g, bn_qkv_b, qkva);
  k_attn<<<dim3(2048), dim3(256), 0, stream>>>(qkva, relA2, relAT2, veA4,
                                               bn_sim_g, bn_sim_b, bn_out_g, bn_out_b, yT);
  k_xs<<<dim3(316), dim3(256), 0, stream>>>(yT, in_w, in_b, xnb, yStd);
  k_mlp1_mfma<<<dim3(4, 128, 2), dim3(256), 0, stream>>>(xnb, w1b, h1b);
  k_mlp2_mfma<<<dim3(256, 1, 2), dim3(256), 0, stream>>>(h1b, w2b, yStd, (float*)d_out);
}

// Round 17
// 122.476 us; speedup vs baseline: 2.0329x; 1.1790x over previous
//
#include <hip/hip_runtime.h>
#include <hip/hip_bf16.h>
#include <hip/hip_fp16.h>

#define GG 8
#define AA 65
#define BB 256

typedef __attribute__((ext_vector_type(8))) short bf16x8;
typedef __attribute__((ext_vector_type(4))) short s16x4;
typedef __attribute__((ext_vector_type(4))) float f32x4;
typedef _Float16 hf2 __attribute__((ext_vector_type(2)));
#define MFMA16(a, b, c) __builtin_amdgcn_mfma_f32_16x16x32_bf16(a, b, c, 0, 0, 0)
#define FDOT2(a, b, c) __builtin_amdgcn_fdot2((a), (b), (c), false)

__device__ __forceinline__ void rz_taps(int o, float scale, int in_size,
                                        int& ia, int& ib, float& f) {
  float pos = (o + 0.5f) * scale - 0.5f;
  float fl = floorf(pos);
  int i0 = (int)fl;
  f = pos - fl;
  ia = i0 < 0 ? 0 : i0;
  int i1 = i0 + 1;
  ib = i1 > (in_size - 1) ? (in_size - 1) : i1;
}

// Compile-time 128->65 tap: pos = (j+0.5)*65/128-0.5 = (130j-63)/256 exactly.
#define JTAP(jc, ja, jb, fj) \
  const int num_ = 130 * (jc) - 63;               \
  const int fl_ = num_ >> 8;                      \
  const int ja = fl_ < 0 ? 0 : fl_;               \
  const int jb = (fl_ + 1 > 64) ? 64 : (fl_ + 1); \
  const float fj = (float)(num_ - (fl_ << 8)) * 0.00390625f;

__device__ __forceinline__ float gelu_exact(float v) {
  return 0.5f * v * (1.0f + erff(v * 0.70710678118654752f));
}

__device__ __forceinline__ short f2b(float f) {
  __hip_bfloat16 h = __float2bfloat16(f);
  return *reinterpret_cast<short*>(&h);
}
__device__ __forceinline__ float b2f(short s) {
  unsigned int u = ((unsigned int)(unsigned short)s) << 16;
  return __uint_as_float(u);
}

#define RSBN 0.99999500003749977f  // 1/sqrt(1+1e-5)

// ---------- PREP: weights->bf16, relA2/relAT2 (fp16 c-pair packed), veA4 ----------
__global__ void k_prep(const float* __restrict__ base, const float* __restrict__ wq,
                       const float* __restrict__ w1, const float* __restrict__ w2,
                       short* __restrict__ wqb, short* __restrict__ w1b,
                       short* __restrict__ w2b, __half* __restrict__ relA2h,
                       __half* __restrict__ relAT2h, __half* __restrict__ veA4) {
  int blk = blockIdx.x;
  int tt = threadIdx.x;
  if (blk < 256) {             // weights
    int i = blk * 256 + tt;
    if (i < 32768) wqb[i] = f2b(wq[i]);
    w1b[i] = f2b(w1[i]);
    w2b[i] = f2b(w2[i]);
    return;
  }
  blk -= 256;
  if (blk < 265) {             // q_emb / k_emb^T, fp16 c-pair dword layout [cp][i][68]
    int idx = blk * 256 + tt;
    if (idx >= 16 * AA * AA) return;
    int j = idx % AA;
    int r = idx / AA;
    int i = r % AA;
    int c = r / AA;
    int ia, ib, ja, jb; float fi, fj;
    rz_taps(i, 255.0f / 65.0f, 255, ia, ib, fi);
    rz_taps(j, 255.0f / 65.0f, 255, ja, jb, fj);
    const float* S = base + (size_t)c * 255 * 255;
    float v = (1.0f - fi) * ((1.0f - fj) * S[ia * 255 + ja] + fj * S[ia * 255 + jb])
            + fi * ((1.0f - fj) * S[ib * 255 + ja] + fj * S[ib * 255 + jb]);
    if (c < 8) {
      relA2h[((((c >> 1) * 4420) + i * 68 + j) << 1) + (c & 1)] = __float2half(v);
    } else {
      int c2 = c - 8;
      relAT2h[((((c2 >> 1) * 4420) + j * 68 + i) << 1) + (c2 & 1)] = __float2half(v);
    }
    return;
  }
  blk -= 265;
  {  // veA4[c][ap4][i] float4-groups (8 halves = 8 a's); wave-coalesced AND x4-vector
    int idx = blk * 256 + tt;  // 16*72*128 = 147,456
    if (idx >= 16 * 72 * 128) return;
    int i = idx & 127;
    int r = idx >> 7;
    int a = r % 72, c = r / 72;
    float v = 0.f;
    if (a < 65) {
      int ia, ib; float fi;
      rz_taps(i, 65.0f / 128.0f, 65, ia, ib, fi);
      int ja, jb; float fj;
      rz_taps(a, 255.0f / 65.0f, 255, ja, jb, fj);
      int p0a, p0b; float g0;
      rz_taps(ia, 255.0f / 65.0f, 255, p0a, p0b, g0);
      int p1a, p1b; float g1;
      rz_taps(ib, 255.0f / 65.0f, 255, p1a, p1b, g1);
      const float* S = base + (size_t)(16 + c) * 255 * 255;
      float r0 = (1.0f - g0) * ((1.0f - fj) * S[p0a * 255 + ja] + fj * S[p0a * 255 + jb])
               + g0 * ((1.0f - fj) * S[p0b * 255 + ja] + fj * S[p0b * 255 + jb]);
      float r1 = (1.0f - g1) * ((1.0f - fj) * S[p1a * 255 + ja] + fj * S[p1a * 255 + jb])
               + g1 * ((1.0f - fj) * S[p1b * 255 + ja] + fj * S[p1b * 255 + jb]);
      v = (1.0f - fi) * r0 + fi * r1;
    }
    veA4[(((size_t)(c * 9 + (a >> 3)) * 128 + i) << 3) + (a & 7)] = __float2half(v);
  }
}

// ---------- MFMA GEMM 1: qkva[n][o][a][w] = bf16(BN(Wqkv . downsample_i(x))) ----------
__global__ __launch_bounds__(256) void k_qkv_mfma(
    const float* __restrict__ x, const short* __restrict__ wqb,
    const float* __restrict__ bg, const float* __restrict__ bb,
    short* __restrict__ out) {
  const int ob = blockIdx.x * 128;
  const int ya = blockIdx.y;           // a*2 + p-half
  const int a = ya >> 1;
  const int pb = (ya & 1) * 64;
  const int n = blockIdx.z;
  __shared__ short Asm[128 * 40];
  __shared__ short Bsm[64 * 40];
  const int t = threadIdx.x;
  const int lane = t & 63, wv = t >> 6;
  const int wm = wv >> 1, wn = wv & 1;
  const int lr = lane & 15, lk = (lane >> 4) * 8;
  int ia, ib; float f;
  rz_taps(a, 128.0f / 65.0f, 128, ia, ib, f);
  const float f0 = 1.0f - f;
  f32x4 acc[4][2];
  #pragma unroll
  for (int i = 0; i < 4; ++i)
    #pragma unroll
    for (int j = 0; j < 2; ++j)
      #pragma unroll
      for (int q = 0; q < 4; ++q) acc[i][j][q] = 0.f;
  const float* X = x + (size_t)n * 128 * 16384;
  for (int k0 = 0; k0 < 128; k0 += 32) {
    #pragma unroll
    for (int i2 = 0; i2 < 2; ++i2) {
      int u = t + 256 * i2;
      int row = u >> 2, kq = (u & 3) * 8;
      *(bf16x8*)&Asm[row * 40 + kq] = *(const bf16x8*)&wqb[(ob + row) * 128 + k0 + kq];
    }
    {
      int k = t >> 3, p8 = (t & 7) * 8;
      int c = k0 + k;
      const float* rowA = X + ((size_t)c * 128 + ia) * 128 + pb + p8;
      const float* rowB = X + ((size_t)c * 128 + ib) * 128 + pb + p8;
      float4 a0 = *(const float4*)rowA;
      float4 a1 = *(const float4*)(rowA + 4);
      float4 b0 = *(const float4*)rowB;
      float4 b1 = *(const float4*)(rowB + 4);
      short* d = &Bsm[p8 * 40 + k];
      d[0 * 40] = f2b(f0 * a0.x + f * b0.x);
      d[1 * 40] = f2b(f0 * a0.y + f * b0.y);
      d[2 * 40] = f2b(f0 * a0.z + f * b0.z);
      d[3 * 40] = f2b(f0 * a0.w + f * b0.w);
      d[4 * 40] = f2b(f0 * a1.x + f * b1.x);
      d[5 * 40] = f2b(f0 * a1.y + f * b1.y);
      d[6 * 40] = f2b(f0 * a1.z + f * b1.z);
      d[7 * 40] = f2b(f0 * a1.w + f * b1.w);
    }
    __syncthreads();
    bf16x8 af[4], bfr[2];
    #pragma unroll
    for (int mf = 0; mf < 4; ++mf) af[mf] = *(bf16x8*)&Asm[(wm * 64 + mf * 16 + lr) * 40 + lk];
    #pragma unroll
    for (int nf = 0; nf < 2; ++nf) bfr[nf] = *(bf16x8*)&Bsm[(wn * 32 + nf * 16 + lr) * 40 + lk];
    #pragma unroll
    for (int mf = 0; mf < 4; ++mf)
      #pragma unroll
      for (int nf = 0; nf < 2; ++nf)
        acc[mf][nf] = MFMA16(af[mf], bfr[nf], acc[mf][nf]);
    __syncthreads();
  }
  #pragma unroll
  for (int mf = 0; mf < 4; ++mf) {
    #pragma unroll
    for (int r = 0; r < 4; ++r) {
      int o = ob + wm * 64 + mf * 16 + (lane >> 4) * 4 + r;
      float sc = bg[o] * RSBN, sh = bb[o];
      #pragma unroll
      for (int nf = 0; nf < 2; ++nf) {
        int p = pb + wn * 32 + nf * 16 + lr;
        out[((size_t)(n * 256 + o) * 65 + a) * 128 + p] = f2b(acc[mf][nf][r] * sc + sh);
      }
    }
  }
}

// ---------- F: fused sim(fp16 dot2) + softmax + x4-dot2 sv/sve + bn_out ----------
// Pinv lives in the spare tail of Ss (beyond PwsH) -> LDS 19,984 B = 8 blocks/CU.
__global__ void k_attn(const short* __restrict__ qkva, const __half* __restrict__ relA2,
                       const __half* __restrict__ relAT2, const __half* __restrict__ veA4,
                       const float* __restrict__ sg, const float* __restrict__ sb,
                       const float* __restrict__ og, const float* __restrict__ ob,
                       float* __restrict__ yT) {
  int orig = blockIdx.x;
  int bg = ((orig & 7) << 8) + (orig >> 3);  // bijective XCD-chunk swizzle
  int b = bg >> 3, g = bg & 7;
  int n = b >> 7, w = b & 127;
  __shared__ __attribute__((aligned(16))) float Ss[65 * 68];  // 17,680 B; PwsH+Pinv after
  __shared__ __attribute__((aligned(16))) float u0[576];      // 2,304 B
  __half* PwsH = (__half*)Ss;            // 128*66 halves = 16,896 B
  float* Pinv2 = Ss + 4224;              // floats 4224..4351 (beyond PwsH, within Ss)
  hf2* qs2 = (hf2*)u0;
  hf2* ks2v = (hf2*)(u0 + 260);
  float* ks2f = u0 + 260;
  __half* vasH = (__half*)u0;
  int t = threadIdx.x;
  const short* Qbase = qkva + ((size_t)(n * 256 + g * 32) * 65) * 128 + w;

  // phase 1: stage q,k as fp16 c-pairs
  for (int l = t; l < 520; l += 256) {
    int isQ = (l < 260);
    int u2 = isQ ? l : l - 260;
    int cp = u2 / 65, a = u2 - cp * 65;
    int cbase = (cp << 1) + (isQ ? 0 : 8);
    float v0 = b2f(Qbase[(size_t)(cbase * 65 + a) * 128]);
    float v1 = b2f(Qbase[(size_t)((cbase + 1) * 65 + a) * 128]);
    hf2 h;
    h[0] = (_Float16)v0;
    h[1] = (_Float16)v1;
    if (isQ) qs2[cp * 65 + a] = h;
    else ks2v[cp * 68 + a] = h;
  }
  __syncthreads();

  // phase 2: sim 65x65 via packed fdot2 (qk+qr+kr, BN-combined)
  {
    float sqk = sg[g] * RSBN, sqr = sg[8 + g] * RSBN, skr = sg[16 + g] * RSBN;
    float badd = sb[g] + sb[8 + g] + sb[16 + g];
    const float* rAf = (const float*)relA2;
    const float* rTf = (const float*)relAT2;
    const hf2* rAv = (const hf2*)relA2;
    const hf2* rTv = (const hf2*)relAT2;
    for (int u = t; u < 65 * 17; u += 256) {
      int i = u / 17, jq = u - i * 17;
      hf2 q2[4];
      #pragma unroll
      for (int cp = 0; cp < 4; ++cp) q2[cp] = qs2[cp * 65 + i];
      if (jq < 16) {
        int j0 = jq * 4;
        int lofs = i * 68 + j0;
        float qk0 = 0, qk1 = 0, qk2 = 0, qk3 = 0;
        float qr0 = 0, qr1 = 0, qr2 = 0, qr3 = 0;
        float kr0 = 0, kr1 = 0, kr2 = 0, kr3 = 0;
        #pragma unroll
        for (int cp = 0; cp < 4; ++cp) {
          float4 kq = *(const float4*)&ks2f[cp * 68 + j0];
          float4 ra = *(const float4*)&rAf[cp * 4420 + lofs];
          float4 rt = *(const float4*)&rTf[cp * 4420 + lofs];
          hf2 k0 = __builtin_bit_cast(hf2, kq.x);
          hf2 k1 = __builtin_bit_cast(hf2, kq.y);
          hf2 k2h = __builtin_bit_cast(hf2, kq.z);
          hf2 k3 = __builtin_bit_cast(hf2, kq.w);
          qk0 = FDOT2(k0, q2[cp], qk0);
          qk1 = FDOT2(k1, q2[cp], qk1);
          qk2 = FDOT2(k2h, q2[cp], qk2);
          qk3 = FDOT2(k3, q2[cp], qk3);
          qr0 = FDOT2(__builtin_bit_cast(hf2, ra.x), q2[cp], qr0);
          qr1 = FDOT2(__builtin_bit_cast(hf2, ra.y), q2[cp], qr1);
          qr2 = FDOT2(__builtin_bit_cast(hf2, ra.z), q2[cp], qr2);
          qr3 = FDOT2(__builtin_bit_cast(hf2, ra.w), q2[cp], qr3);
          kr0 = FDOT2(__builtin_bit_cast(hf2, rt.x), k0, kr0);
          kr1 = FDOT2(__builtin_bit_cast(hf2, rt.y), k1, kr1);
          kr2 = FDOT2(__builtin_bit_cast(hf2, rt.z), k2h, kr2);
          kr3 = FDOT2(__builtin_bit_cast(hf2, rt.w), k3, kr3);
        }
        float4 res;
        res.x = sqk * qk0 + sqr * qr0 + skr * kr0 + badd;
        res.y = sqk * qk1 + sqr * qr1 + skr * kr1 + badd;
        res.z = sqk * qk2 + sqr * qr2 + skr * kr2 + badd;
        res.w = sqk * qk3 + sqr * qr3 + skr * kr3 + badd;
        *(float4*)&Ss[lofs] = res;
      } else {
        int lofs = i * 68 + 64;
        float qk = 0, qr = 0, kr = 0;
        #pragma unroll
        for (int cp = 0; cp < 4; ++cp) {
          hf2 kv = ks2v[cp * 68 + 64];
          qk = FDOT2(kv, q2[cp], qk);
          qr = FDOT2(rAv[cp * 4420 + lofs], q2[cp], qr);
          kr = FDOT2(rTv[cp * 4420 + lofs], kv, kr);
        }
        Ss[lofs] = sqk * qk + sqr * qr + skr * kr + badd;
      }
    }
  }
  __syncthreads();

  // phase 3: v stage (fp16, a padded to 72, overlays u0) + register-T softmax fold
  for (int l = t; l < 16 * 72; l += 256) {
    int c = l / 72, a = l - c * 72;
    float v = (a < 65) ? b2f(Qbase[(size_t)((16 + c) * 65 + a) * 128]) : 0.f;
    vasH[l] = __float2half(v);
  }
  {
    const int i = t >> 1, h = t & 1;
    int ia, ib; float fi;
    rz_taps(i, 65.0f / 128.0f, 65, ia, ib, fi);
    const float* r0 = Ss + ia * 68 + h * 32;
    const float* r1 = Ss + ib * 68 + h * 32;
    const float wi0 = 1.0f - fi;
    float T[33];
    #pragma unroll
    for (int k4 = 0; k4 < 8; ++k4) {
      float4 a4 = *(const float4*)(r0 + 4 * k4);
      float4 b4 = *(const float4*)(r1 + 4 * k4);
      T[4 * k4 + 0] = wi0 * a4.x + fi * b4.x;
      T[4 * k4 + 1] = wi0 * a4.y + fi * b4.y;
      T[4 * k4 + 2] = wi0 * a4.z + fi * b4.z;
      T[4 * k4 + 3] = wi0 * a4.w + fi * b4.w;
    }
    T[32] = wi0 * r0[32] + fi * r1[32];
    float mx = T[0];
    #pragma unroll
    for (int k = 1; k < 33; ++k) mx = fmaxf(mx, T[k]);
    mx = fmaxf(mx, __shfl_xor(mx, 1));
    float p[33];
    #pragma unroll
    for (int k = 0; k < 33; ++k) p[k] = 0.f;
    float sum = 0.f;
    if (h == 0) {
      #pragma unroll
      for (int j = 0; j < 64; ++j) {
        JTAP(j, ja, jb, fj);
        float v = (1.0f - fj) * T[ja] + fj * T[jb];
        float e = __expf(v - mx);
        sum += e;
        p[ja] += e * (1.0f - fj);
        p[jb] += e * fj;
      }
    } else {
      #pragma unroll
      for (int j = 64; j < 128; ++j) {
        JTAP(j, ja, jb, fj);
        float v = (1.0f - fj) * T[ja - 32] + fj * T[jb - 32];
        float e = __expf(v - mx);
        sum += e;
        p[ja - 32] += e * (1.0f - fj);
        p[jb - 32] += e * fj;
      }
    }
    sum += __shfl_xor(sum, 1);
    float other = __shfl_xor(h ? p[0] : p[32], 1);
    __syncthreads();   // all Ss reads complete before Pw/Pinv overwrite the same LDS
    __half* prow = &PwsH[i * 66];
    if (h == 0) {
      p[32] += other;
      #pragma unroll
      for (int k = 0; k < 33; ++k) prow[k] = __float2half(p[k]);
      Pinv2[i] = 1.0f / sum;
    } else {
      p[0] += other;
      #pragma unroll
      for (int k = 0; k < 33; ++k) prow[32 + k] = __float2half(p[k]);
      prow[65] = __float2half(0.f);
    }
  }
  __syncthreads();

  // phase 4: x4-vectorized dot2 (float4 LDS vas + float4 coalesced veA4)
  {
    const int i = t & 127;
    const int cg = t >> 7;
    const float inv = Pinv2[i];
    hf2 pw[33];
    const hf2* prow2 = (const hf2*)&PwsH[i * 66];
    #pragma unroll
    for (int ap = 0; ap < 33; ++ap) pw[ap] = prow2[ap];
    #pragma unroll
    for (int l = 0; l < 8; ++l) {
      const int c = cg * 8 + l;
      const float4* vr4 = (const float4*)&vasH[c * 72];
      const float4* vp4 = (const float4*)veA4 + (size_t)(c * 9) * 128 + i;
      float sv0 = 0.f, sv1 = 0.f, se0 = 0.f, se1 = 0.f;
      #pragma unroll
      for (int q4 = 0; q4 < 8; ++q4) {
        float4 a4 = vr4[q4];
        float4 b4 = vp4[(size_t)q4 * 128];
        sv0 = FDOT2(__builtin_bit_cast(hf2, a4.x), pw[4 * q4 + 0], sv0);
        sv1 = FDOT2(__builtin_bit_cast(hf2, a4.y), pw[4 * q4 + 1], sv1);
        sv0 = FDOT2(__builtin_bit_cast(hf2, a4.z), pw[4 * q4 + 2], sv0);
        sv1 = FDOT2(__builtin_bit_cast(hf2, a4.w), pw[4 * q4 + 3], sv1);
        se0 = FDOT2(__builtin_bit_cast(hf2, b4.x), pw[4 * q4 + 0], se0);
        se1 = FDOT2(__builtin_bit_cast(hf2, b4.y), pw[4 * q4 + 1], se1);
        se0 = FDOT2(__builtin_bit_cast(hf2, b4.z), pw[4 * q4 + 2], se0);
        se1 = FDOT2(__builtin_bit_cast(hf2, b4.w), pw[4 * q4 + 3], se1);
      }
      {  // tail: ap=32
        float4 a4 = vr4[8];
        float4 b4 = vp4[(size_t)8 * 128];
        sv0 = FDOT2(__builtin_bit_cast(hf2, a4.x), pw[32], sv0);
        se0 = FDOT2(__builtin_bit_cast(hf2, b4.x), pw[32], se0);
      }
      float sv = sv0 + sv1, se = se0 + se1;
      int c2 = g * 16 + c;
      int o0 = 2 * c2;
      float val = og[o0] * RSBN * (sv * inv) + ob[o0]
                + og[o0 + 1] * RSBN * (se * inv) + ob[o0 + 1];
      yT[((size_t)(n * 128 + c2)) * 16384 + w * 128 + i] = val;
    }
  }
}

// ---------- XS: stage yT plane (fp32 LDS), emit xnb (shift+IN, bf16) + yStd (fp32) ----------
__global__ __launch_bounds__(256) void k_xs(const float* __restrict__ yT,
                                            const float* __restrict__ inw,
                                            const float* __restrict__ inb,
                                            short* __restrict__ xnb,
                                            float* __restrict__ yStd) {
  int gid = blockIdx.x;
  int n, cs, cx = -1;
  bool wStd;
  if (gid < 256) {
    n = gid >> 7; cx = gid & 127;
    cs = (cx < 40) ? (cx % 10) : cx;
    wStd = (cx < 10) || (cx >= 40);
  } else {
    int u = gid - 256;
    n = u / 30; cs = 10 + (u % 30);
    wStd = true;
  }
  int dh = 0, dw = 0;
  if (cx >= 0) {
    if (cx < 10)       dw = -2;
    else if (cx < 20)  dw = 2;
    else if (cx < 30)  dh = -2;
    else if (cx < 40)  dh = 2;
  }
  __shared__ float Sb[128 * 130];
  __shared__ float sm[8];
  const float* src = yT + ((size_t)(n * 128 + cs)) * 16384;
  int t = threadIdx.x;
  #pragma unroll
  for (int l = 0; l < 16; ++l) {
    int q = t + l * 256;
    float4 v = *(const float4*)&src[q * 4];
    int w = q >> 5, i0 = (q * 4) & 127;
    float* d = &Sb[w * 130 + i0];
    *(float2*)d = make_float2(v.x, v.y);
    *(float2*)(d + 2) = make_float2(v.z, v.w);
  }
  __syncthreads();
  if (wStd) {
    float* dst = yStd + ((size_t)(n * 128 + cs)) * 16384;
    for (int l = 0; l < 64; ++l) {
      int idx = t + l * 256;
      int h = idx >> 7, w = idx & 127;
      dst[idx] = Sb[w * 130 + h];
    }
  }
  if (cx >= 0) {
    float s = 0.f, q2 = 0.f;
    for (int l = 0; l < 64; ++l) {
      int idx = t + l * 256;
      int h = idx >> 7, w = idx & 127;
      int hs = h + dh, ws = w + dw;
      float v = (hs >= 0 && hs < 128 && ws >= 0 && ws < 128) ? Sb[ws * 130 + hs] : 0.f;
      s += v; q2 += v * v;
    }
    #pragma unroll
    for (int o = 32; o; o >>= 1) { s += __shfl_down(s, o); q2 += __shfl_down(q2, o); }
    if ((t & 63) == 0) { sm[(t >> 6) * 2] = s; sm[(t >> 6) * 2 + 1] = q2; }
    __syncthreads();
    float S_ = sm[0] + sm[2] + sm[4] + sm[6];
    float Q_ = sm[1] + sm[3] + sm[5] + sm[7];
    float mean = S_ * (1.0f / 16384.0f);
    float var = Q_ * (1.0f / 16384.0f) - mean * mean;
    float scale = inw[cx] * rsqrtf(var + 1e-5f);
    float shift = inb[cx] - mean * scale;
    short* dst = xnb + ((size_t)(n * 128 + cx)) * 16384;
    for (int l = 0; l < 64; ++l) {
      int idx = t + l * 256;
      int h = idx >> 7, w = idx & 127;
      int hs = h + dh, ws = w + dw;
      float v = (hs >= 0 && hs < 128 && ws >= 0 && ws < 128) ? Sb[ws * 130 + hs] : 0.f;
      dst[idx] = f2b(v * scale + shift);
    }
  }
}

// ---------- FUSED MLP: out = W2 . gelu(W1 . xn) + yStd  (no h1 round-trip) ----------
__global__ __launch_bounds__(256) void k_mlp(
    const short* __restrict__ xnb, const short* __restrict__ w1b,
    const short* __restrict__ w2b, const float* __restrict__ y,
    float* __restrict__ out) {
  const int pb = blockIdx.x * 64;
  const int n = blockIdx.z;
  __shared__ short Asm[128 * 40];      // 10,240 B: w1/w2 chunk staging
  __shared__ short Bxn[64 * 136];      // 17,408 B: xn [p][c], persistent
  __shared__ short h1s[64 * 136];      // 17,408 B: h1 chunk [p][o]
  const int t = threadIdx.x;
  const int lane = t & 63, wv = t >> 6;
  const int wm = wv >> 1, wn = wv & 1;
  const int lr = lane & 15, lk = (lane >> 4) * 8;
  const short* X = xnb + (size_t)n * 128 * 16384;
  // stage xn once: [64 p][136-pad c]
  #pragma unroll
  for (int i4 = 0; i4 < 4; ++i4) {
    int u = t + 256 * i4;               // 1024: c = u>>3, p0 = (u&7)*8
    int c = u >> 3, p0 = (u & 7) * 8;
    bf16x8 hv = *(const bf16x8*)&X[(size_t)c * 16384 + pb + p0];
    #pragma unroll
    for (int j = 0; j < 8; ++j) Bxn[(p0 + j) * 136 + c] = hv[j];
  }
  f32x4 acc2[4][2];
  #pragma unroll
  for (int i = 0; i < 4; ++i)
    #pragma unroll
    for (int j = 0; j < 2; ++j)
      #pragma unroll
      for (int q = 0; q < 4; ++q) acc2[i][j][q] = 0.f;
  __syncthreads();

  for (int och = 0; och < 4; ++och) {
    // ---- GEMM1: h1c[128 o][64 p] = w1[och] . xn ----
    f32x4 acc1[4][2];
    #pragma unroll
    for (int i = 0; i < 4; ++i)
      #pragma unroll
      for (int j = 0; j < 2; ++j)
        #pragma unroll
        for (int q = 0; q < 4; ++q) acc1[i][j][q] = 0.f;
    for (int c0 = 0; c0 < 128; c0 += 32) {
      #pragma unroll
      for (int i2 = 0; i2 < 2; ++i2) {
        int u = t + 256 * i2;
        int row = u >> 2, kq = (u & 3) * 8;
        *(bf16x8*)&Asm[row * 40 + kq] =
            *(const bf16x8*)&w1b[(och * 128 + row) * 128 + c0 + kq];
      }
      __syncthreads();
      bf16x8 af[4], bfr[2];
      #pragma unroll
      for (int mf = 0; mf < 4; ++mf)
        af[mf] = *(bf16x8*)&Asm[(wm * 64 + mf * 16 + lr) * 40 + lk];
      #pragma unroll
      for (int nf = 0; nf < 2; ++nf)
        bfr[nf] = *(bf16x8*)&Bxn[(wn * 32 + nf * 16 + lr) * 136 + c0 + lk];
      #pragma unroll
      for (int mf = 0; mf < 4; ++mf)
        #pragma unroll
        for (int nf = 0; nf < 2; ++nf)
          acc1[mf][nf] = MFMA16(af[mf], bfr[nf], acc1[mf][nf]);
      __syncthreads();
    }
    // ---- gelu -> h1s[p][o] (bf16) ----
    #pragma unroll
    for (int mf = 0; mf < 4; ++mf)
      #pragma unroll
      for (int r = 0; r < 4; ++r) {
        int o = wm * 64 + mf * 16 + (lane >> 4) * 4 + r;
        #pragma unroll
        for (int nf = 0; nf < 2; ++nf) {
          int p = wn * 32 + nf * 16 + lr;
          h1s[p * 136 + o] = f2b(gelu_exact(acc1[mf][nf][r]));
        }
      }
    // ---- GEMM2: acc2 += w2[:, och-chunk] . h1s ----
    for (int k0 = 0; k0 < 128; k0 += 32) {
      #pragma unroll
      for (int i2 = 0; i2 < 2; ++i2) {
        int u = t + 256 * i2;
        int row = u >> 2, kq = (u & 3) * 8;
        *(bf16x8*)&Asm[row * 40 + kq] =
            *(const bf16x8*)&w2b[row * 512 + och * 128 + k0 + kq];
      }
      __syncthreads();
      bf16x8 af[4], bfr[2];
      #pragma unroll
      for (int mf = 0; mf < 4; ++mf)
        af[mf] = *(bf16x8*)&Asm[(wm * 64 + mf * 16 + lr) * 40 + lk];
      #pragma unroll
      for (int nf = 0; nf < 2; ++nf)
        bfr[nf] = *(bf16x8*)&h1s[(wn * 32 + nf * 16 + lr) * 136 + k0 + lk];
      #pragma unroll
      for (int mf = 0; mf < 4; ++mf)
        #pragma unroll
        for (int nf = 0; nf < 2; ++nf)
          acc2[mf][nf] = MFMA16(af[mf], bfr[nf], acc2[mf][nf]);
      __syncthreads();
    }
  }
  #pragma unroll
  for (int mf = 0; mf < 4; ++mf)
    #pragma unroll
    for (int r = 0; r < 4; ++r) {
      int o = wm * 64 + mf * 16 + (lane >> 4) * 4 + r;
      #pragma unroll
      for (int nf = 0; nf < 2; ++nf) {
        int p = pb + wn * 32 + nf * 16 + lr;
        size_t base = ((size_t)(n * 128 + o)) * 16384 + p;
        out[base] = acc2[mf][nf][r] + y[base];
      }
    }
}

extern "C" void kernel_launch(void* const* d_in, const int* in_sizes, int n_in,
                              void* d_out, int out_size, void* d_ws, size_t ws_size,
                              hipStream_t stream) {
  const float* x        = (const float*)d_in[0];
  const float* w_qkv    = (const float*)d_in[1];
  const float* bn_qkv_g = (const float*)d_in[2];
  const float* bn_qkv_b = (const float*)d_in[3];
  const float* bn_sim_g = (const float*)d_in[4];
  const float* bn_sim_b = (const float*)d_in[5];
  const float* bn_out_g = (const float*)d_in[6];
  const float* bn_out_b = (const float*)d_in[7];
  const float* in_w     = (const float*)d_in[8];
  const float* in_b     = (const float*)d_in[9];
  const float* mlp_w1   = (const float*)d_in[10];
  const float* mlp_w2   = (const float*)d_in[11];
  const float* base_rel = (const float*)d_in[12];
  float* Wp = (float*)d_ws;

  __half* relA2  = (__half*)(Wp + 0);        // 17,680 f
  __half* relAT2 = (__half*)(Wp + 17680);    // 17,680 f
  __half* veA4   = (__half*)(Wp + 35360);    // 147,456 halves = 73,728 f
  float* yT      = Wp + 109088;              // 4,194,304
  float* yStd    = Wp + 4303392;             // 4,194,304
  short* wqb     = (short*)(Wp + 8497696);   // 32,768 shorts
  short* w1b     = (short*)(Wp + 8514080);   // 65,536 shorts
  short* w2b     = (short*)(Wp + 8546848);   // 65,536 shorts
  short* xnb     = (short*)(Wp + 8579616);   // 4,194,304 shorts
  short* qkva    = (short*)(Wp + 10676768);  // 4,259,840 shorts
  // peak: 12,806,688 floats = 51.2 MB

  k_prep<<<dim3(1097), dim3(256), 0, stream>>>(base_rel, w_qkv, mlp_w1, mlp_w2,
                                               wqb, w1b, w2b, relA2, relAT2, veA4);
  k_qkv_mfma<<<dim3(2, 130, 2), dim3(256), 0, stream>>>(x, wqb, bn_qkv_g, bn_qkv_b, qkva);
  k_attn<<<dim3(2048), dim3(256), 0, stream>>>(qkva, relA2, relAT2, veA4,
                                               bn_sim_g, bn_sim_b, bn_out_g, bn_out_b, yT);
  k_xs<<<dim3(316), dim3(256), 0, stream>>>(yT, in_w, in_b, xnb, yStd);
  k_mlp<<<dim3(256, 1, 2), dim3(256), 0, stream>>>(xnb, w1b, w2b, yStd, (float*)d_out);
}